// Round 2
// baseline (1720.743 us; speedup 1.0000x reference)
//
#include <hip/hip_runtime.h>
#include <hip/hip_bf16.h>

#define N_NODES 20000
#define E_EDGES 320000
#define E_TOT   (E_EDGES + N_NODES)
#define IN_CH   128
#define HID     256
#define HEADS   8
#define CPH     32

#define BM 64
#define BN 64
#define BK 16

enum { EP_BIAS = 0, EP_BN_LRELU = 1, EP_LRELU = 2 };

// ---------------- tiled GEMM: C = epilogue(A@W + b) ----------------
// A is fp32 [M,K1] (+ optional A2 [M,K2] concatenated along K), W fp32 [K1+K2, Nc]
__global__ __launch_bounds__(256)
void gemm_kernel(const float* __restrict__ A1, int K1,
                 const float* __restrict__ A2, int K2,
                 const float* __restrict__ W,
                 const float* __restrict__ bias,
                 const float* __restrict__ bng,
                 const float* __restrict__ bnb,
                 float* __restrict__ Cout,
                 int M, int Nc, int mode)
{
    const int K = K1 + K2;
    __shared__ float As[BK][BM + 1];
    __shared__ float Ws[BK][BN + 1];
    int tid = threadIdx.x;
    int bm = blockIdx.x * BM;
    int bn = blockIdx.y * BN;
    int tx = tid & 15, ty = tid >> 4;
    float acc[4][4] = {};

    for (int k0 = 0; k0 < K; k0 += BK) {
#pragma unroll
        for (int i = 0; i < 4; ++i) {             // A tile: 64 rows x 16 k
            int idx = tid + i * 256;
            int r = idx >> 4, kk = idx & 15;
            int row = bm + r, k = k0 + kk;
            float v = 0.f;
            if (row < M) v = (k < K1) ? A1[(size_t)row * K1 + k] : A2[(size_t)row * K2 + (k - K1)];
            As[kk][r] = v;
        }
#pragma unroll
        for (int i = 0; i < 4; ++i) {             // W tile: 16 k x 64 cols
            int idx = tid + i * 256;
            int kk = idx >> 6, cc = idx & 63;
            Ws[kk][cc] = W[(size_t)(k0 + kk) * Nc + bn + cc];
        }
        __syncthreads();
#pragma unroll
        for (int kk = 0; kk < BK; ++kk) {
            float a[4], w[4];
#pragma unroll
            for (int i = 0; i < 4; ++i) a[i] = As[kk][ty * 4 + i];
#pragma unroll
            for (int j = 0; j < 4; ++j) w[j] = Ws[kk][tx * 4 + j];
#pragma unroll
            for (int i = 0; i < 4; ++i)
#pragma unroll
                for (int j = 0; j < 4; ++j) acc[i][j] += a[i] * w[j];
        }
        __syncthreads();
    }

#pragma unroll
    for (int j = 0; j < 4; ++j) {
        int col = bn + tx * 4 + j;
        float bv = bias[col];
        float sc = 1.f, sh = 0.f;
        if (mode == EP_BN_LRELU) {
            sc = bng[col] * rsqrtf(1.f + 1e-5f);
            sh = bnb[col];
        }
#pragma unroll
        for (int i = 0; i < 4; ++i) {
            int row = bm + ty * 4 + i;
            if (row < M) {
                float v = acc[i][j] + bv;
                if (mode == EP_BN_LRELU) { v = v * sc + sh; v = v > 0.f ? v : 0.1f * v; }
                else if (mode == EP_LRELU) { v = v > 0.f ? v : 0.1f * v; }
                Cout[(size_t)row * Nc + col] = v;
            }
        }
    }
}

// ---------------- CSR build ----------------
__global__ void deg_init_kernel(int* __restrict__ cnt) {
    int i = blockIdx.x * 256 + threadIdx.x;
    if (i < N_NODES) cnt[i] = 1;   // self loop
}
__global__ void deg_count_kernel(const int* __restrict__ dst, int* __restrict__ cnt) {
    int e = blockIdx.x * 256 + threadIdx.x;
    if (e < E_EDGES) atomicAdd(&cnt[dst[e]], 1);
}
__global__ __launch_bounds__(1024)
void scan_kernel(const int* __restrict__ cnt, int* __restrict__ off) {
    __shared__ int lds[1024];
    __shared__ int carry;
    int tid = threadIdx.x;
    if (tid == 0) carry = 0;
    __syncthreads();
    for (int base = 0; base < N_NODES; base += 1024) {
        int i = base + tid;
        int v = (i < N_NODES) ? cnt[i] : 0;
        lds[tid] = v;
        __syncthreads();
        for (int st = 1; st < 1024; st <<= 1) {
            int a = (tid >= st) ? lds[tid - st] : 0;
            __syncthreads();
            lds[tid] += a;
            __syncthreads();
        }
        if (i < N_NODES) off[i] = carry + lds[tid] - v;
        __syncthreads();
        if (tid == 1023) carry += lds[1023];
        __syncthreads();
    }
    if (tid == 0) off[N_NODES] = carry;
}
__global__ void self_fill_kernel(const int* __restrict__ off, int* __restrict__ fill, int* __restrict__ csr) {
    int i = blockIdx.x * 256 + threadIdx.x;
    if (i < N_NODES) { csr[off[i]] = i; fill[i] = 1; }
}
__global__ void edge_fill_kernel(const int* __restrict__ src, const int* __restrict__ dst,
                                 const int* __restrict__ off, int* __restrict__ fill, int* __restrict__ csr) {
    int e = blockIdx.x * 256 + threadIdx.x;
    if (e < E_EDGES) {
        int d = dst[e];
        int pos = atomicAdd(&fill[d], 1);
        csr[off[d] + pos] = src[e];
    }
}

// ---------------- fused GATv2 aggregation: online softmax + bias + LN + lrelu + residual ----------------
__global__ __launch_bounds__(256)
void gat_agg_kernel(const float* __restrict__ xl, const float* __restrict__ xr,
                    float* __restrict__ g,
                    const int* __restrict__ off, const int* __restrict__ csr,
                    const float* __restrict__ att,
                    const float* __restrict__ bias,
                    const float* __restrict__ lng,
                    const float* __restrict__ lnb)
{
    int n = blockIdx.x;
    int t = threadIdx.x;                 // t = h*32 + c
    float xrv = xr[(size_t)n * HID + t];
    float av = att[t];
    float m = -INFINITY, s = 0.f, o = 0.f;
    int beg = off[n], end = off[n + 1];
    for (int p = beg; p < end; ++p) {
        int sidx = csr[p];
        float xlv = xl[(size_t)sidx * HID + t];
        float v = xlv + xrv;
        v = v > 0.f ? v : 0.2f * v;      // leaky 0.2
        float pr = av * v;
#pragma unroll
        for (int d = 16; d; d >>= 1) pr += __shfl_xor(pr, d, 32);   // per-head logit
        float nm = fmaxf(m, pr);
        float f = __expf(m - nm);        // first iter: exp(-inf)=0
        float e = __expf(pr - nm);
        s = s * f + e;
        o = o * f + e * xlv;
        m = nm;
    }
    float y = o / (s + 1e-16f) + bias[t];
    // LayerNorm over 256 channels
    __shared__ float r1[4], r2[4];
    float s1 = y, s2 = y * y;
#pragma unroll
    for (int d = 32; d; d >>= 1) { s1 += __shfl_xor(s1, d, 64); s2 += __shfl_xor(s2, d, 64); }
    if ((t & 63) == 0) { r1[t >> 6] = s1; r2[t >> 6] = s2; }
    __syncthreads();
    float mu  = (r1[0] + r1[1] + r1[2] + r1[3]) * (1.f / HID);
    float ex2 = (r2[0] + r2[1] + r2[2] + r2[3]) * (1.f / HID);
    float var = ex2 - mu * mu;
    float nv = (y - mu) * rsqrtf(var + 1e-5f) * lng[t] + lnb[t];
    nv = nv > 0.f ? nv : 0.1f * nv;      // lrelu 0.1
    g[(size_t)n * HID + t] = nv + g[(size_t)n * HID + t];
}

// ---------------- final head dot: [N,64] @ [64,1] + b ----------------
__global__ __launch_bounds__(256)
void head_final_kernel(const float* __restrict__ t3, const float* __restrict__ w4,
                       const float* __restrict__ b4, float* __restrict__ out)
{
    int row = blockIdx.x * 4 + (threadIdx.x >> 6);
    int lane = threadIdx.x & 63;
    float v = 0.f;
    if (row < N_NODES) v = t3[(size_t)row * 64 + lane] * w4[lane];
#pragma unroll
    for (int d = 32; d; d >>= 1) v += __shfl_xor(v, d, 64);
    if (row < N_NODES && lane == 0) out[row] = v + b4[0];
}

static inline size_t align_up(size_t v, size_t a) { return (v + a - 1) & ~(a - 1); }

extern "C" void kernel_launch(void* const* d_in, const int* in_sizes, int n_in,
                              void* d_out, int out_size, void* d_ws, size_t ws_size,
                              hipStream_t stream)
{
    const float* x      = (const float*)d_in[0];
    const int*   ei     = (const int*)d_in[1];
    const float* mlp_w1 = (const float*)d_in[2];
    const float* mlp_b1 = (const float*)d_in[3];
    const float* bn1_g  = (const float*)d_in[4];
    const float* bn1_b  = (const float*)d_in[5];
    const float* mlp_w2 = (const float*)d_in[6];
    const float* mlp_b2 = (const float*)d_in[7];
    const float* bn2_g  = (const float*)d_in[8];
    const float* bn2_b  = (const float*)d_in[9];
    const float* mlp_w3 = (const float*)d_in[10];
    const float* mlp_b3 = (const float*)d_in[11];
    const float* gat_wl = (const float*)d_in[12];
    const float* gat_bl = (const float*)d_in[13];
    const float* gat_wr = (const float*)d_in[14];
    const float* gat_br = (const float*)d_in[15];
    const float* gat_att  = (const float*)d_in[16];
    const float* gat_bias = (const float*)d_in[17];
    const float* ln_g   = (const float*)d_in[18];
    const float* ln_b   = (const float*)d_in[19];
    const float* head_w1 = (const float*)d_in[20];
    const float* head_b1 = (const float*)d_in[21];
    const float* hbn1_g  = (const float*)d_in[22];
    const float* hbn1_b  = (const float*)d_in[23];
    const float* head_w2 = (const float*)d_in[24];
    const float* head_b2 = (const float*)d_in[25];
    const float* hbn2_g  = (const float*)d_in[26];
    const float* hbn2_b  = (const float*)d_in[27];
    const float* head_w3 = (const float*)d_in[28];
    const float* head_b3 = (const float*)d_in[29];
    const float* head_w4 = (const float*)d_in[30];
    const float* head_b4 = (const float*)d_in[31];
    float* out = (float*)d_out;

    // ---- workspace layout (~84 MB) ----
    char* w = (char*)d_ws;
    size_t p = 0;
    int* off  = (int*)(w + p); p = align_up(p + (N_NODES + 1) * sizeof(int), 64);
    int* fill = (int*)(w + p); p = align_up(p + N_NODES * sizeof(int), 64);
    int* csr  = (int*)(w + p); p = align_up(p + E_TOT * sizeof(int), 64);
    float* bufA  = (float*)(w + p); p = align_up(p + (size_t)N_NODES * HID * 4, 64);
    float* bufB  = (float*)(w + p); p = align_up(p + (size_t)N_NODES * HID * 4, 64);
    float* x_mlp = (float*)(w + p); p = align_up(p + (size_t)N_NODES * HID * 4, 64);
    float* g     = (float*)(w + p); p = align_up(p + (size_t)N_NODES * HID * 4, 64);
    (void)ws_size; (void)in_sizes; (void)n_in; (void)out_size;

    const int* e_src = ei;
    const int* e_dst = ei + E_EDGES;

    dim3 blk(256);
    dim3 gNH((N_NODES + BM - 1) / BM, HID / BN);      // 313 x 4

    // ---- MLP stem ----
    gemm_kernel<<<gNH, blk, 0, stream>>>(x, IN_CH, nullptr, 0, mlp_w1, mlp_b1, bn1_g, bn1_b, bufA, N_NODES, HID, EP_BN_LRELU);
    gemm_kernel<<<gNH, blk, 0, stream>>>(bufA, HID, nullptr, 0, mlp_w2, mlp_b2, bn2_g, bn2_b, bufB, N_NODES, HID, EP_BN_LRELU);
    gemm_kernel<<<gNH, blk, 0, stream>>>(bufB, HID, nullptr, 0, mlp_w3, mlp_b3, nullptr, nullptr, x_mlp, N_NODES, HID, EP_BIAS);
    hipMemcpyAsync(g, x_mlp, (size_t)N_NODES * HID * 4, hipMemcpyDeviceToDevice, stream);

    // ---- CSR by destination ----
    deg_init_kernel<<<(N_NODES + 255) / 256, blk, 0, stream>>>(fill);
    deg_count_kernel<<<(E_EDGES + 255) / 256, blk, 0, stream>>>(e_dst, fill);
    scan_kernel<<<1, 1024, 0, stream>>>(fill, off);
    self_fill_kernel<<<(N_NODES + 255) / 256, blk, 0, stream>>>(off, fill, csr);
    edge_fill_kernel<<<(E_EDGES + 255) / 256, blk, 0, stream>>>(e_src, e_dst, off, fill, csr);

    // ---- GAT layers ----
    for (int i = 0; i < 4; ++i) {
        gemm_kernel<<<gNH, blk, 0, stream>>>(g, HID, nullptr, 0, gat_wl + (size_t)i * HID * HID,
                                             gat_bl + i * HID, nullptr, nullptr, bufA, N_NODES, HID, EP_BIAS);
        gemm_kernel<<<gNH, blk, 0, stream>>>(g, HID, nullptr, 0, gat_wr + (size_t)i * HID * HID,
                                             gat_br + i * HID, nullptr, nullptr, bufB, N_NODES, HID, EP_BIAS);
        gat_agg_kernel<<<N_NODES, blk, 0, stream>>>(bufA, bufB, g, off, csr,
                                                    gat_att + i * HID, gat_bias + i * HID,
                                                    ln_g + i * HID, ln_b + i * HID);
    }

    // ---- regression head ----
    gemm_kernel<<<gNH, blk, 0, stream>>>(x_mlp, HID, g, HID, head_w1, head_b1, hbn1_g, hbn1_b, bufA, N_NODES, HID, EP_BN_LRELU);
    dim3 gN2((N_NODES + BM - 1) / BM, 128 / BN);
    gemm_kernel<<<gN2, blk, 0, stream>>>(bufA, HID, nullptr, 0, head_w2, head_b2, hbn2_g, hbn2_b, bufB, N_NODES, 128, EP_BN_LRELU);
    dim3 gN3((N_NODES + BM - 1) / BM, 1);
    gemm_kernel<<<gN3, blk, 0, stream>>>(bufB, 128, nullptr, 0, head_w3, head_b3, nullptr, nullptr, bufA, N_NODES, 64, EP_LRELU);
    head_final_kernel<<<(N_NODES + 3) / 4, blk, 0, stream>>>(bufA, head_w4, head_b4, out);
}

// Round 4
// 1288.371 us; speedup vs baseline: 1.3356x; 1.3356x over previous
//
#include <hip/hip_runtime.h>
#include <hip/hip_bf16.h>

#define N_NODES 20000
#define E_EDGES 320000
#define E_TOT   (E_EDGES + N_NODES)
#define IN_CH   128
#define HID     256
#define HEADS   8
#define CPH     32

// MFMA GEMM tile
#define BM 128
#define BN 64
#define BK 64
#define LDA 72   // BK + 8 pad (bf16 elems) -> row stride 144 B (16B-aligned, 2-way banks max)

enum { EP_BIAS = 0, EP_BN_LRELU = 1, EP_LRELU = 2 };

typedef short bf16x8 __attribute__((ext_vector_type(8)));
typedef float f32x4  __attribute__((ext_vector_type(4)));

__device__ __forceinline__ unsigned short f2bf(float f) {
    union { __hip_bfloat16 h; unsigned short u; } cv;
    cv.h = __float2bfloat16(f);
    return cv.u;
}
__device__ __forceinline__ float bf2f(unsigned short u) {
    union { unsigned short u; __hip_bfloat16 h; } cv;
    cv.u = u;
    return __bfloat162float(cv.h);
}

// ---------------- weight prep: fp32 [K,Nc] -> split bf16 transposed [Nc,K] (hi, lo) ----------------
struct WDesc { const float* src; unsigned short* dhi; unsigned short* dlo; int K; int Nc; };
struct WDescs { WDesc d[14]; };

__global__ __launch_bounds__(256)
void wprep_kernel(WDescs ds) {
    WDesc w = ds.d[blockIdx.y];
    int total = w.K * w.Nc;
    int i = blockIdx.x * 256 + threadIdx.x;
    if (i < total) {
        int n = i / w.K;
        int k = i - n * w.K;
        float s = w.src[(size_t)k * w.Nc + n];
        unsigned short hi = f2bf(s);
        w.dhi[i] = hi;
        w.dlo[i] = f2bf(s - bf2f(hi));
    }
}

// ---------------- split-bf16 MFMA GEMM: C = epilogue(A@W + b) ----------------
// A fp32 [M,K1] (+ optional A2 [M,K2] concat along K), W split-bf16 transposed [Nc,K] hi/lo
__global__ __launch_bounds__(256)
void gemm_kernel(const float* __restrict__ A1, int K1,
                 const float* __restrict__ A2, int K2,
                 const unsigned short* __restrict__ Whi,
                 const unsigned short* __restrict__ Wlo,
                 const float* __restrict__ bias,
                 const float* __restrict__ bng,
                 const float* __restrict__ bnb,
                 float* __restrict__ Cout,
                 int M, int Nc, int mode)
{
    const int K = K1 + K2;
    __shared__ unsigned short AsH[BM][LDA];
    __shared__ unsigned short AsL[BM][LDA];
    __shared__ unsigned short WsH[BN][LDA];
    __shared__ unsigned short WsL[BN][LDA];
    const int tid  = threadIdx.x;
    const int wave = tid >> 6;
    const int lane = tid & 63;
    const int bm = blockIdx.x * BM;
    const int bn = blockIdx.y * BN;

    f32x4 acc[2][4];
#pragma unroll
    for (int i = 0; i < 2; ++i)
#pragma unroll
        for (int j = 0; j < 4; ++j) acc[i][j] = (f32x4){0.f, 0.f, 0.f, 0.f};

    for (int k0 = 0; k0 < K; k0 += BK) {
        // stage A tile: 128 rows x 64 k (fp32 -> bf16 hi + lo)
#pragma unroll
        for (int i = 0; i < 8; ++i) {
            int idx = i * 256 + tid;          // 0..2047
            int r   = idx >> 4;               // 0..127
            int c4  = (idx & 15) << 2;        // 0,4,..,60
            int row = bm + r, k = k0 + c4;    // K1 % 64 == 0 -> float4 never straddles
            float4 v = make_float4(0.f, 0.f, 0.f, 0.f);
            if (row < M) {
                const float* src = (k < K1) ? &A1[(size_t)row * K1 + k]
                                            : &A2[(size_t)row * K2 + (k - K1)];
                v = *(const float4*)src;
            }
            ushort4 h = { f2bf(v.x), f2bf(v.y), f2bf(v.z), f2bf(v.w) };
            ushort4 l = { f2bf(v.x - bf2f(h.x)), f2bf(v.y - bf2f(h.y)),
                          f2bf(v.z - bf2f(h.z)), f2bf(v.w - bf2f(h.w)) };
            *(ushort4*)&AsH[r][c4] = h;
            *(ushort4*)&AsL[r][c4] = l;
        }
        // stage W tile: 64 cols x 64 k (already split bf16, transposed)
#pragma unroll
        for (int i = 0; i < 4; ++i) {
            int idx = i * 256 + tid;          // 0..1023
            int r   = idx >> 4;               // 0..63
            int c4  = (idx & 15) << 2;
            size_t goff = (size_t)(bn + r) * K + k0 + c4;
            *(ushort4*)&WsH[r][c4] = *(const ushort4*)&Whi[goff];
            *(ushort4*)&WsL[r][c4] = *(const ushort4*)&Wlo[goff];
        }
        __syncthreads();
#pragma unroll
        for (int ks = 0; ks < 2; ++ks) {
            int krow = ks * 32 + (lane >> 4) * 8;
            int ra0 = wave * 32 + (lane & 15);
            bf16x8 a0h = *(const bf16x8*)&AsH[ra0][krow];
            bf16x8 a1h = *(const bf16x8*)&AsH[ra0 + 16][krow];
            bf16x8 a0l = *(const bf16x8*)&AsL[ra0][krow];
            bf16x8 a1l = *(const bf16x8*)&AsL[ra0 + 16][krow];
#pragma unroll
            for (int ct = 0; ct < 4; ++ct) {
                int rb = ct * 16 + (lane & 15);
                bf16x8 bh = *(const bf16x8*)&WsH[rb][krow];
                bf16x8 bl = *(const bf16x8*)&WsL[rb][krow];
                acc[0][ct] = __builtin_amdgcn_mfma_f32_16x16x32_bf16(a0h, bh, acc[0][ct], 0, 0, 0);
                acc[0][ct] = __builtin_amdgcn_mfma_f32_16x16x32_bf16(a0h, bl, acc[0][ct], 0, 0, 0);
                acc[0][ct] = __builtin_amdgcn_mfma_f32_16x16x32_bf16(a0l, bh, acc[0][ct], 0, 0, 0);
                acc[1][ct] = __builtin_amdgcn_mfma_f32_16x16x32_bf16(a1h, bh, acc[1][ct], 0, 0, 0);
                acc[1][ct] = __builtin_amdgcn_mfma_f32_16x16x32_bf16(a1h, bl, acc[1][ct], 0, 0, 0);
                acc[1][ct] = __builtin_amdgcn_mfma_f32_16x16x32_bf16(a1l, bh, acc[1][ct], 0, 0, 0);
            }
        }
        __syncthreads();
    }

    // epilogue: C/D layout col=lane&15, row=(lane>>4)*4+reg
    const int r0 = bm + wave * 32 + ((lane >> 4) << 2);
    const int c0 = bn + (lane & 15);
#pragma unroll
    for (int ct = 0; ct < 4; ++ct) {
        int col = c0 + ct * 16;
        float bv = bias[col];
        float sc = 1.f, sh = 0.f;
        if (mode == EP_BN_LRELU) {
            sc = bng[col] * rsqrtf(1.f + 1e-5f);
            sh = bnb[col];
        }
#pragma unroll
        for (int rt = 0; rt < 2; ++rt) {
#pragma unroll
            for (int reg = 0; reg < 4; ++reg) {
                int row = r0 + rt * 16 + reg;
                if (row < M) {
                    float v = acc[rt][ct][reg] + bv;
                    if (mode == EP_BN_LRELU) { v = v * sc + sh; v = v > 0.f ? v : 0.1f * v; }
                    else if (mode == EP_LRELU) { v = v > 0.f ? v : 0.1f * v; }
                    Cout[(size_t)row * Nc + col] = v;
                }
            }
        }
    }
}

// ---------------- CSR build ----------------
__global__ void deg_init_kernel(int* __restrict__ cnt) {
    int i = blockIdx.x * 256 + threadIdx.x;
    if (i < N_NODES) cnt[i] = 1;   // self loop
}
__global__ void deg_count_kernel(const int* __restrict__ dst, int* __restrict__ cnt) {
    int e = blockIdx.x * 256 + threadIdx.x;
    if (e < E_EDGES) atomicAdd(&cnt[dst[e]], 1);
}
__global__ __launch_bounds__(1024)
void scan_kernel(const int* __restrict__ cnt, int* __restrict__ off) {
    __shared__ int lds[1024];
    __shared__ int carry;
    int tid = threadIdx.x;
    if (tid == 0) carry = 0;
    __syncthreads();
    for (int base = 0; base < N_NODES; base += 1024) {
        int i = base + tid;
        int v = (i < N_NODES) ? cnt[i] : 0;
        lds[tid] = v;
        __syncthreads();
        for (int st = 1; st < 1024; st <<= 1) {
            int a = (tid >= st) ? lds[tid - st] : 0;
            __syncthreads();
            lds[tid] += a;
            __syncthreads();
        }
        if (i < N_NODES) off[i] = carry + lds[tid] - v;
        __syncthreads();
        if (tid == 1023) carry += lds[1023];
        __syncthreads();
    }
    if (tid == 0) off[N_NODES] = carry;
}
__global__ void self_fill_kernel(const int* __restrict__ off, int* __restrict__ fill, int* __restrict__ csr) {
    int i = blockIdx.x * 256 + threadIdx.x;
    if (i < N_NODES) { csr[off[i]] = i; fill[i] = 1; }
}
__global__ void edge_fill_kernel(const int* __restrict__ src, const int* __restrict__ dst,
                                 const int* __restrict__ off, int* __restrict__ fill, int* __restrict__ csr) {
    int e = blockIdx.x * 256 + threadIdx.x;
    if (e < E_EDGES) {
        int d = dst[e];
        int pos = atomicAdd(&fill[d], 1);
        csr[off[d] + pos] = src[e];
    }
}

// ---------------- fused GATv2 aggregation: online softmax + bias + LN + lrelu + residual ----------------
__global__ __launch_bounds__(256)
void gat_agg_kernel(const float* __restrict__ xl, const float* __restrict__ xr,
                    float* __restrict__ g,
                    const int* __restrict__ off, const int* __restrict__ csr,
                    const float* __restrict__ att,
                    const float* __restrict__ bias,
                    const float* __restrict__ lng,
                    const float* __restrict__ lnb)
{
    int n = blockIdx.x;
    int t = threadIdx.x;                 // t = h*32 + c
    float xrv = xr[(size_t)n * HID + t];
    float av = att[t];
    float m = -INFINITY, s = 0.f, o = 0.f;
    int beg = off[n], end = off[n + 1];
    for (int p = beg; p < end; ++p) {
        int sidx = csr[p];
        float xlv = xl[(size_t)sidx * HID + t];
        float v = xlv + xrv;
        v = v > 0.f ? v : 0.2f * v;      // leaky 0.2
        float pr = av * v;
#pragma unroll
        for (int d = 16; d; d >>= 1) pr += __shfl_xor(pr, d, 32);   // per-head logit
        float nm = fmaxf(m, pr);
        float f = __expf(m - nm);        // first iter: exp(-inf)=0
        float e = __expf(pr - nm);
        s = s * f + e;
        o = o * f + e * xlv;
        m = nm;
    }
    float y = o / (s + 1e-16f) + bias[t];
    // LayerNorm over 256 channels
    __shared__ float r1[4], r2[4];
    float s1 = y, s2 = y * y;
#pragma unroll
    for (int d = 32; d; d >>= 1) { s1 += __shfl_xor(s1, d, 64); s2 += __shfl_xor(s2, d, 64); }
    if ((t & 63) == 0) { r1[t >> 6] = s1; r2[t >> 6] = s2; }
    __syncthreads();
    float mu  = (r1[0] + r1[1] + r1[2] + r1[3]) * (1.f / HID);
    float ex2 = (r2[0] + r2[1] + r2[2] + r2[3]) * (1.f / HID);
    float var = ex2 - mu * mu;
    float nv = (y - mu) * rsqrtf(var + 1e-5f) * lng[t] + lnb[t];
    nv = nv > 0.f ? nv : 0.1f * nv;      // lrelu 0.1
    g[(size_t)n * HID + t] = nv + g[(size_t)n * HID + t];
}

// ---------------- final head dot: [N,64] @ [64,1] + b ----------------
__global__ __launch_bounds__(256)
void head_final_kernel(const float* __restrict__ t3, const float* __restrict__ w4,
                       const float* __restrict__ b4, float* __restrict__ out)
{
    int row = blockIdx.x * 4 + (threadIdx.x >> 6);
    int lane = threadIdx.x & 63;
    float v = 0.f;
    if (row < N_NODES) v = t3[(size_t)row * 64 + lane] * w4[lane];
#pragma unroll
    for (int d = 32; d; d >>= 1) v += __shfl_xor(v, d, 64);
    if (row < N_NODES && lane == 0) out[row] = v + b4[0];
}

static inline size_t align_up(size_t v, size_t a) { return (v + a - 1) & ~(a - 1); }

extern "C" void kernel_launch(void* const* d_in, const int* in_sizes, int n_in,
                              void* d_out, int out_size, void* d_ws, size_t ws_size,
                              hipStream_t stream)
{
    const float* x      = (const float*)d_in[0];
    const int*   ei     = (const int*)d_in[1];
    const float* mlp_w1 = (const float*)d_in[2];
    const float* mlp_b1 = (const float*)d_in[3];
    const float* bn1_g  = (const float*)d_in[4];
    const float* bn1_b  = (const float*)d_in[5];
    const float* mlp_w2 = (const float*)d_in[6];
    const float* mlp_b2 = (const float*)d_in[7];
    const float* bn2_g  = (const float*)d_in[8];
    const float* bn2_b  = (const float*)d_in[9];
    const float* mlp_w3 = (const float*)d_in[10];
    const float* mlp_b3 = (const float*)d_in[11];
    const float* gat_wl = (const float*)d_in[12];
    const float* gat_bl = (const float*)d_in[13];
    const float* gat_wr = (const float*)d_in[14];
    const float* gat_br = (const float*)d_in[15];
    const float* gat_att  = (const float*)d_in[16];
    const float* gat_bias = (const float*)d_in[17];
    const float* ln_g   = (const float*)d_in[18];
    const float* ln_b   = (const float*)d_in[19];
    const float* head_w1 = (const float*)d_in[20];
    const float* head_b1 = (const float*)d_in[21];
    const float* hbn1_g  = (const float*)d_in[22];
    const float* hbn1_b  = (const float*)d_in[23];
    const float* head_w2 = (const float*)d_in[24];
    const float* head_b2 = (const float*)d_in[25];
    const float* hbn2_g  = (const float*)d_in[26];
    const float* hbn2_b  = (const float*)d_in[27];
    const float* head_w3 = (const float*)d_in[28];
    const float* head_b3 = (const float*)d_in[29];
    const float* head_w4 = (const float*)d_in[30];
    const float* head_b4 = (const float*)d_in[31];
    float* out = (float*)d_out;

    // ---- workspace layout ----
    char* w = (char*)d_ws;
    size_t p = 0;
    int* off  = (int*)(w + p); p = align_up(p + (N_NODES + 1) * sizeof(int), 64);
    int* fill = (int*)(w + p); p = align_up(p + N_NODES * sizeof(int), 64);
    int* csr  = (int*)(w + p); p = align_up(p + E_TOT * sizeof(int), 64);
    float* bufA  = (float*)(w + p); p = align_up(p + (size_t)N_NODES * HID * 4, 64);
    float* bufB  = (float*)(w + p); p = align_up(p + (size_t)N_NODES * HID * 4, 64);
    float* x_mlp = (float*)(w + p); p = align_up(p + (size_t)N_NODES * HID * 4, 64);
    float* g     = (float*)(w + p); p = align_up(p + (size_t)N_NODES * HID * 4, 64);
    // split-bf16 transposed weights (hi, lo)
    auto walloc = [&](size_t elems) {
        unsigned short* q = (unsigned short*)(w + p);
        p = align_up(p + elems * 2, 64);
        return q;
    };
    unsigned short* wt_mlp1_h = walloc((size_t)IN_CH * HID);
    unsigned short* wt_mlp1_l = walloc((size_t)IN_CH * HID);
    unsigned short* wt_mlp2_h = walloc((size_t)HID * HID);
    unsigned short* wt_mlp2_l = walloc((size_t)HID * HID);
    unsigned short* wt_mlp3_h = walloc((size_t)HID * HID);
    unsigned short* wt_mlp3_l = walloc((size_t)HID * HID);
    unsigned short *wt_gl_h[4], *wt_gl_l[4], *wt_gr_h[4], *wt_gr_l[4];
    for (int i = 0; i < 4; ++i) {
        wt_gl_h[i] = walloc((size_t)HID * HID);
        wt_gl_l[i] = walloc((size_t)HID * HID);
        wt_gr_h[i] = walloc((size_t)HID * HID);
        wt_gr_l[i] = walloc((size_t)HID * HID);
    }
    unsigned short* wt_h1_h = walloc((size_t)2 * HID * HID);
    unsigned short* wt_h1_l = walloc((size_t)2 * HID * HID);
    unsigned short* wt_h2_h = walloc((size_t)HID * (HID / 2));
    unsigned short* wt_h2_l = walloc((size_t)HID * (HID / 2));
    unsigned short* wt_h3_h = walloc((size_t)(HID / 2) * (HID / 4));
    unsigned short* wt_h3_l = walloc((size_t)(HID / 2) * (HID / 4));
    (void)ws_size; (void)in_sizes; (void)n_in; (void)out_size;

    const int* e_src = ei;
    const int* e_dst = ei + E_EDGES;

    dim3 blk(256);
    dim3 gNH((N_NODES + BM - 1) / BM, HID / BN);      // 157 x 4

    // ---- weight prep (fp32 -> split bf16 transposed) ----
    WDescs ds;
    ds.d[0]  = { mlp_w1, wt_mlp1_h, wt_mlp1_l, IN_CH, HID };
    ds.d[1]  = { mlp_w2, wt_mlp2_h, wt_mlp2_l, HID, HID };
    ds.d[2]  = { mlp_w3, wt_mlp3_h, wt_mlp3_l, HID, HID };
    for (int i = 0; i < 4; ++i) {
        ds.d[3 + i] = { gat_wl + (size_t)i * HID * HID, wt_gl_h[i], wt_gl_l[i], HID, HID };
        ds.d[7 + i] = { gat_wr + (size_t)i * HID * HID, wt_gr_h[i], wt_gr_l[i], HID, HID };
    }
    ds.d[11] = { head_w1, wt_h1_h, wt_h1_l, 2 * HID, HID };
    ds.d[12] = { head_w2, wt_h2_h, wt_h2_l, HID, HID / 2 };
    ds.d[13] = { head_w3, wt_h3_h, wt_h3_l, HID / 2, HID / 4 };
    {
        dim3 gp((2 * HID * HID + 255) / 256, 14);     // max matrix = 131072 elems
        wprep_kernel<<<gp, blk, 0, stream>>>(ds);
    }

    // ---- CSR by destination (independent of MLP; do it early) ----
    deg_init_kernel<<<(N_NODES + 255) / 256, blk, 0, stream>>>(fill);
    deg_count_kernel<<<(E_EDGES + 255) / 256, blk, 0, stream>>>(e_dst, fill);
    scan_kernel<<<1, 1024, 0, stream>>>(fill, off);
    self_fill_kernel<<<(N_NODES + 255) / 256, blk, 0, stream>>>(off, fill, csr);
    edge_fill_kernel<<<(E_EDGES + 255) / 256, blk, 0, stream>>>(e_src, e_dst, off, fill, csr);

    // ---- MLP stem ----
    gemm_kernel<<<gNH, blk, 0, stream>>>(x, IN_CH, nullptr, 0, wt_mlp1_h, wt_mlp1_l, mlp_b1, bn1_g, bn1_b, bufA, N_NODES, HID, EP_BN_LRELU);
    gemm_kernel<<<gNH, blk, 0, stream>>>(bufA, HID, nullptr, 0, wt_mlp2_h, wt_mlp2_l, mlp_b2, bn2_g, bn2_b, bufB, N_NODES, HID, EP_BN_LRELU);
    gemm_kernel<<<gNH, blk, 0, stream>>>(bufB, HID, nullptr, 0, wt_mlp3_h, wt_mlp3_l, mlp_b3, nullptr, nullptr, x_mlp, N_NODES, HID, EP_BIAS);
    hipMemcpyAsync(g, x_mlp, (size_t)N_NODES * HID * 4, hipMemcpyDeviceToDevice, stream);

    // ---- GAT layers ----
    for (int i = 0; i < 4; ++i) {
        gemm_kernel<<<gNH, blk, 0, stream>>>(g, HID, nullptr, 0, wt_gl_h[i], wt_gl_l[i],
                                             gat_bl + i * HID, nullptr, nullptr, bufA, N_NODES, HID, EP_BIAS);
        gemm_kernel<<<gNH, blk, 0, stream>>>(g, HID, nullptr, 0, wt_gr_h[i], wt_gr_l[i],
                                             gat_br + i * HID, nullptr, nullptr, bufB, N_NODES, HID, EP_BIAS);
        gat_agg_kernel<<<N_NODES, blk, 0, stream>>>(bufA, bufB, g, off, csr,
                                                    gat_att + i * HID, gat_bias + i * HID,
                                                    ln_g + i * HID, ln_b + i * HID);
    }

    // ---- regression head ----
    gemm_kernel<<<gNH, blk, 0, stream>>>(x_mlp, HID, g, HID, wt_h1_h, wt_h1_l, head_b1, hbn1_g, hbn1_b, bufA, N_NODES, HID, EP_BN_LRELU);
    dim3 gN2((N_NODES + BM - 1) / BM, 128 / BN);
    gemm_kernel<<<gN2, blk, 0, stream>>>(bufA, HID, nullptr, 0, wt_h2_h, wt_h2_l, head_b2, hbn2_g, hbn2_b, bufB, N_NODES, 128, EP_BN_LRELU);
    dim3 gN3((N_NODES + BM - 1) / BM, 1);
    gemm_kernel<<<gN3, blk, 0, stream>>>(bufB, 128, nullptr, 0, wt_h3_h, wt_h3_l, head_b3, nullptr, nullptr, bufA, N_NODES, 64, EP_LRELU);
    head_final_kernel<<<(N_NODES + 3) / 4, blk, 0, stream>>>(bufA, head_w4, head_b4, out);
}

// Round 5
// 980.306 us; speedup vs baseline: 1.7553x; 1.3143x over previous
//
#include <hip/hip_runtime.h>
#include <hip/hip_bf16.h>

#define N_NODES 20000
#define E_EDGES 320000
#define E_TOT   (E_EDGES + N_NODES)
#define IN_CH   128
#define HID     256
#define HEADS   8
#define CPH     32

#define LDA 72   // 64 + 8 pad (f16 elems): 144-B row stride, conflict-benign

enum { EP_BIAS = 0, EP_BN_LRELU = 1, EP_LRELU = 2 };

typedef _Float16 f16;
typedef f16  f16x2 __attribute__((ext_vector_type(2)));
typedef f16  f16x4 __attribute__((ext_vector_type(4)));
typedef f16  f16x8 __attribute__((ext_vector_type(8)));
typedef float f32x4 __attribute__((ext_vector_type(4)));

// ---------------- weight prep: fp32 [K,Nc] -> fp16 transposed [Nc,K] ----------------
struct WDesc { const float* src; f16* dst; int K; int Nc; };
struct WDescs { WDesc d[14]; };

__global__ __launch_bounds__(256)
void wprep_kernel(WDescs ds) {
    WDesc w = ds.d[blockIdx.y];
    int total = w.K * w.Nc;
    int i = blockIdx.x * 256 + threadIdx.x;
    if (i < total) {
        int n = i / w.K;
        int k = i - n * w.K;
        w.dst[i] = (f16)w.src[(size_t)k * w.Nc + n];
    }
}

// ---------------- fp16 MFMA GEMM: C = epilogue(A@W + b) ----------------
// A fp32 [M,K1] (+ optional A2 [M,K2] concat along K), Wt fp16 transposed [Nc,K]
// BM=64 (4 waves x 16 rows), BN = NT*16 = full Nc (A staged ONCE per block)
template<int NT>
__global__ __launch_bounds__(256, 2)
void gemm_kernel(const float* __restrict__ A1, int K1,
                 const float* __restrict__ A2, int K2,
                 const f16* __restrict__ Wt,
                 const float* __restrict__ bias,
                 const float* __restrict__ bng,
                 const float* __restrict__ bnb,
                 void* __restrict__ Cout,
                 int M, int mode, int f16out)
{
    const int Nc = NT * 16;
    const int K = K1 + K2;
    __shared__ f16 As[64][LDA];
    __shared__ f16 Ws[NT * 16][LDA];
    const int tid  = threadIdx.x;
    const int wave = tid >> 6;
    const int lane = tid & 63;
    const int bm = blockIdx.x * 64;

    f32x4 acc[NT];
#pragma unroll
    for (int j = 0; j < NT; ++j) acc[j] = (f32x4){0.f, 0.f, 0.f, 0.f};

    for (int k0 = 0; k0 < K; k0 += 64) {
        // stage A tile: 64 rows x 64 k (fp32 -> fp16)
#pragma unroll
        for (int i = 0; i < 4; ++i) {
            int idx = i * 256 + tid;          // 0..1023
            int r   = idx >> 4;               // 0..63
            int c4  = (idx & 15) << 2;        // 0,4,..,60
            int row = bm + r, k = k0 + c4;    // K1 % 64 == 0 -> float4 never straddles
            float4 v = make_float4(0.f, 0.f, 0.f, 0.f);
            if (row < M) {
                const float* src = (k < K1) ? &A1[(size_t)row * K1 + k]
                                            : &A2[(size_t)row * K2 + (k - K1)];
                v = *(const float4*)src;
            }
            f16x4 h; h[0] = (f16)v.x; h[1] = (f16)v.y; h[2] = (f16)v.z; h[3] = (f16)v.w;
            *(f16x4*)&As[r][c4] = h;
        }
        // stage W tile: Nc rows x 64 k (already fp16, transposed)
#pragma unroll
        for (int i = 0; i < NT; ++i) {
            int idx = i * 256 + tid;
            int r   = idx >> 4;               // 0..Nc-1
            int c4  = (idx & 15) << 2;
            *(f16x4*)&Ws[r][c4] = *(const f16x4*)&Wt[(size_t)r * K + k0 + c4];
        }
        __syncthreads();
#pragma unroll
        for (int ks = 0; ks < 2; ++ks) {
            int krow = ks * 32 + (lane >> 4) * 8;
            f16x8 a = *(const f16x8*)&As[wave * 16 + (lane & 15)][krow];
#pragma unroll
            for (int ct = 0; ct < NT; ++ct) {
                f16x8 b = *(const f16x8*)&Ws[ct * 16 + (lane & 15)][krow];
                acc[ct] = __builtin_amdgcn_mfma_f32_16x16x32_f16(a, b, acc[ct], 0, 0, 0);
            }
        }
        __syncthreads();
    }

    // epilogue: C/D layout col=lane&15, row=(lane>>4)*4+reg
    const int r0 = bm + wave * 16 + ((lane >> 4) << 2);
    const int c0 = lane & 15;
#pragma unroll
    for (int ct = 0; ct < NT; ++ct) {
        int col = c0 + ct * 16;
        float bv = bias[col];
        float sc = 1.f, sh = 0.f;
        if (mode == EP_BN_LRELU) {
            sc = bng[col] * rsqrtf(1.f + 1e-5f);
            sh = bnb[col];
        }
#pragma unroll
        for (int reg = 0; reg < 4; ++reg) {
            int row = r0 + reg;
            if (row < M) {
                float v = acc[ct][reg] + bv;
                if (mode == EP_BN_LRELU) { v = v * sc + sh; v = v > 0.f ? v : 0.1f * v; }
                else if (mode == EP_LRELU) { v = v > 0.f ? v : 0.1f * v; }
                if (f16out) ((f16*)Cout)[(size_t)row * Nc + col] = (f16)v;
                else        ((float*)Cout)[(size_t)row * Nc + col] = v;
            }
        }
    }
}

// ---------------- CSR build ----------------
__global__ void deg_init_kernel(int* __restrict__ cnt) {
    int i = blockIdx.x * 256 + threadIdx.x;
    if (i < N_NODES) cnt[i] = 1;   // self loop
}
__global__ void deg_count_kernel(const int* __restrict__ dst, int* __restrict__ cnt) {
    int e = blockIdx.x * 256 + threadIdx.x;
    if (e < E_EDGES) atomicAdd(&cnt[dst[e]], 1);
}
__global__ __launch_bounds__(1024)
void scan_kernel(const int* __restrict__ cnt, int* __restrict__ off) {
    __shared__ int lds[1024];
    __shared__ int carry;
    int tid = threadIdx.x;
    if (tid == 0) carry = 0;
    __syncthreads();
    for (int base = 0; base < N_NODES; base += 1024) {
        int i = base + tid;
        int v = (i < N_NODES) ? cnt[i] : 0;
        lds[tid] = v;
        __syncthreads();
        for (int st = 1; st < 1024; st <<= 1) {
            int a = (tid >= st) ? lds[tid - st] : 0;
            __syncthreads();
            lds[tid] += a;
            __syncthreads();
        }
        if (i < N_NODES) off[i] = carry + lds[tid] - v;
        __syncthreads();
        if (tid == 1023) carry += lds[1023];
        __syncthreads();
    }
    if (tid == 0) off[N_NODES] = carry;
}
__global__ void self_fill_kernel(const int* __restrict__ off, int* __restrict__ fill, int* __restrict__ csr) {
    int i = blockIdx.x * 256 + threadIdx.x;
    if (i < N_NODES) { csr[off[i]] = i; fill[i] = 1; }
}
__global__ void edge_fill_kernel(const int* __restrict__ src, const int* __restrict__ dst,
                                 const int* __restrict__ off, int* __restrict__ fill, int* __restrict__ csr) {
    int e = blockIdx.x * 256 + threadIdx.x;
    if (e < E_EDGES) {
        int d = dst[e];
        int pos = atomicAdd(&fill[d], 1);
        csr[off[d] + pos] = src[e];
    }
}

// ---------------- fused GATv2 aggregation (fp16 gather, 128 thr = 2 ch/thread) ----------------
__global__ __launch_bounds__(128)
void gat_agg_kernel(const f16* __restrict__ xl, const f16* __restrict__ xr,
                    float* __restrict__ g,
                    const int* __restrict__ off, const int* __restrict__ csr,
                    const float* __restrict__ att,
                    const float* __restrict__ bias,
                    const float* __restrict__ lng,
                    const float* __restrict__ lnb)
{
    int n = blockIdx.x;
    int t = threadIdx.x;                 // 0..127; channels 2t, 2t+1; head = t>>4
    f16x2 xr2 = ((const f16x2*)xr)[(size_t)n * 128 + t];
    float xr0 = (float)xr2[0], xr1 = (float)xr2[1];
    float av0 = att[2 * t], av1 = att[2 * t + 1];
    float m = -INFINITY, s = 0.f, o0 = 0.f, o1 = 0.f;
    int beg = off[n], end = off[n + 1];
    for (int p = beg; p < end; ++p) {
        int sidx = csr[p];
        f16x2 xl2 = ((const f16x2*)xl)[(size_t)sidx * 128 + t];
        float x0 = (float)xl2[0], x1 = (float)xl2[1];
        float v0 = x0 + xr0; v0 = v0 > 0.f ? v0 : 0.2f * v0;
        float v1 = x1 + xr1; v1 = v1 > 0.f ? v1 : 0.2f * v1;
        float pr = av0 * v0 + av1 * v1;
#pragma unroll
        for (int d = 8; d; d >>= 1) pr += __shfl_xor(pr, d, 16);   // per-head (16 lanes)
        float nm = fmaxf(m, pr);
        float f = __expf(m - nm);        // first iter: exp(-inf)=0
        float e = __expf(pr - nm);
        s = s * f + e;
        o0 = o0 * f + e * x0;
        o1 = o1 * f + e * x1;
        m = nm;
    }
    float inv = 1.f / (s + 1e-16f);
    float y0 = o0 * inv + bias[2 * t];
    float y1 = o1 * inv + bias[2 * t + 1];
    // LayerNorm over 256 channels (2 waves)
    __shared__ float r1[2], r2[2];
    float s1 = y0 + y1, s2 = y0 * y0 + y1 * y1;
#pragma unroll
    for (int d = 32; d; d >>= 1) { s1 += __shfl_xor(s1, d, 64); s2 += __shfl_xor(s2, d, 64); }
    if ((t & 63) == 0) { r1[t >> 6] = s1; r2[t >> 6] = s2; }
    __syncthreads();
    float mu  = (r1[0] + r1[1]) * (1.f / HID);
    float ex2 = (r2[0] + r2[1]) * (1.f / HID);
    float rstd = rsqrtf(ex2 - mu * mu + 1e-5f);
    float nv0 = (y0 - mu) * rstd * lng[2 * t] + lnb[2 * t];
    float nv1 = (y1 - mu) * rstd * lng[2 * t + 1] + lnb[2 * t + 1];
    nv0 = nv0 > 0.f ? nv0 : 0.1f * nv0;
    nv1 = nv1 > 0.f ? nv1 : 0.1f * nv1;
    float2 gv = ((float2*)g)[(size_t)n * 128 + t];
    ((float2*)g)[(size_t)n * 128 + t] = make_float2(nv0 + gv.x, nv1 + gv.y);
}

// ---------------- final head dot: [N,64] @ [64,1] + b ----------------
__global__ __launch_bounds__(256)
void head_final_kernel(const float* __restrict__ t3, const float* __restrict__ w4,
                       const float* __restrict__ b4, float* __restrict__ out)
{
    int row = blockIdx.x * 4 + (threadIdx.x >> 6);
    int lane = threadIdx.x & 63;
    float v = 0.f;
    if (row < N_NODES) v = t3[(size_t)row * 64 + lane] * w4[lane];
#pragma unroll
    for (int d = 32; d; d >>= 1) v += __shfl_xor(v, d, 64);
    if (row < N_NODES && lane == 0) out[row] = v + b4[0];
}

static inline size_t align_up(size_t v, size_t a) { return (v + a - 1) & ~(a - 1); }

extern "C" void kernel_launch(void* const* d_in, const int* in_sizes, int n_in,
                              void* d_out, int out_size, void* d_ws, size_t ws_size,
                              hipStream_t stream)
{
    const float* x      = (const float*)d_in[0];
    const int*   ei     = (const int*)d_in[1];
    const float* mlp_w1 = (const float*)d_in[2];
    const float* mlp_b1 = (const float*)d_in[3];
    const float* bn1_g  = (const float*)d_in[4];
    const float* bn1_b  = (const float*)d_in[5];
    const float* mlp_w2 = (const float*)d_in[6];
    const float* mlp_b2 = (const float*)d_in[7];
    const float* bn2_g  = (const float*)d_in[8];
    const float* bn2_b  = (const float*)d_in[9];
    const float* mlp_w3 = (const float*)d_in[10];
    const float* mlp_b3 = (const float*)d_in[11];
    const float* gat_wl = (const float*)d_in[12];
    const float* gat_bl = (const float*)d_in[13];
    const float* gat_wr = (const float*)d_in[14];
    const float* gat_br = (const float*)d_in[15];
    const float* gat_att  = (const float*)d_in[16];
    const float* gat_bias = (const float*)d_in[17];
    const float* ln_g   = (const float*)d_in[18];
    const float* ln_b   = (const float*)d_in[19];
    const float* head_w1 = (const float*)d_in[20];
    const float* head_b1 = (const float*)d_in[21];
    const float* hbn1_g  = (const float*)d_in[22];
    const float* hbn1_b  = (const float*)d_in[23];
    const float* head_w2 = (const float*)d_in[24];
    const float* head_b2 = (const float*)d_in[25];
    const float* hbn2_g  = (const float*)d_in[26];
    const float* hbn2_b  = (const float*)d_in[27];
    const float* head_w3 = (const float*)d_in[28];
    const float* head_b3 = (const float*)d_in[29];
    const float* head_w4 = (const float*)d_in[30];
    const float* head_b4 = (const float*)d_in[31];
    float* out = (float*)d_out;

    // ---- workspace layout ----
    char* w = (char*)d_ws;
    size_t p = 0;
    int* off  = (int*)(w + p); p = align_up(p + (N_NODES + 1) * sizeof(int), 64);
    int* fill = (int*)(w + p); p = align_up(p + N_NODES * sizeof(int), 64);
    int* csr  = (int*)(w + p); p = align_up(p + E_TOT * sizeof(int), 64);
    float* bufA  = (float*)(w + p); p = align_up(p + (size_t)N_NODES * HID * 4, 64);
    float* bufB  = (float*)(w + p); p = align_up(p + (size_t)N_NODES * HID * 4, 64);
    float* x_mlp = (float*)(w + p); p = align_up(p + (size_t)N_NODES * HID * 4, 64);
    float* g     = (float*)(w + p); p = align_up(p + (size_t)N_NODES * HID * 4, 64);
    f16* bufA16 = (f16*)(w + p); p = align_up(p + (size_t)N_NODES * HID * 2, 64);
    f16* bufB16 = (f16*)(w + p); p = align_up(p + (size_t)N_NODES * HID * 2, 64);
    auto walloc = [&](size_t elems) {
        f16* q = (f16*)(w + p);
        p = align_up(p + elems * 2, 64);
        return q;
    };
    f16* wt_mlp1 = walloc((size_t)IN_CH * HID);
    f16* wt_mlp2 = walloc((size_t)HID * HID);
    f16* wt_mlp3 = walloc((size_t)HID * HID);
    f16 *wt_gl[4], *wt_gr[4];
    for (int i = 0; i < 4; ++i) {
        wt_gl[i] = walloc((size_t)HID * HID);
        wt_gr[i] = walloc((size_t)HID * HID);
    }
    f16* wt_h1 = walloc((size_t)2 * HID * HID);
    f16* wt_h2 = walloc((size_t)HID * (HID / 2));
    f16* wt_h3 = walloc((size_t)(HID / 2) * (HID / 4));
    (void)ws_size; (void)in_sizes; (void)n_in; (void)out_size;

    const int* e_src = ei;
    const int* e_dst = ei + E_EDGES;

    dim3 blk(256);
    dim3 gM((N_NODES + 63) / 64);      // 313

    // ---- weight prep (fp32 -> fp16 transposed) ----
    WDescs ds;
    ds.d[0]  = { mlp_w1, wt_mlp1, IN_CH, HID };
    ds.d[1]  = { mlp_w2, wt_mlp2, HID, HID };
    ds.d[2]  = { mlp_w3, wt_mlp3, HID, HID };
    for (int i = 0; i < 4; ++i) {
        ds.d[3 + i] = { gat_wl + (size_t)i * HID * HID, wt_gl[i], HID, HID };
        ds.d[7 + i] = { gat_wr + (size_t)i * HID * HID, wt_gr[i], HID, HID };
    }
    ds.d[11] = { head_w1, wt_h1, 2 * HID, HID };
    ds.d[12] = { head_w2, wt_h2, HID, HID / 2 };
    ds.d[13] = { head_w3, wt_h3, HID / 2, HID / 4 };
    {
        dim3 gp((2 * HID * HID + 255) / 256, 14);
        wprep_kernel<<<gp, blk, 0, stream>>>(ds);
    }

    // ---- CSR by destination ----
    deg_init_kernel<<<(N_NODES + 255) / 256, blk, 0, stream>>>(fill);
    deg_count_kernel<<<(E_EDGES + 255) / 256, blk, 0, stream>>>(e_dst, fill);
    scan_kernel<<<1, 1024, 0, stream>>>(fill, off);
    self_fill_kernel<<<(N_NODES + 255) / 256, blk, 0, stream>>>(off, fill, csr);
    edge_fill_kernel<<<(E_EDGES + 255) / 256, blk, 0, stream>>>(e_src, e_dst, off, fill, csr);

    // ---- MLP stem ----
    gemm_kernel<16><<<gM, blk, 0, stream>>>(x, IN_CH, nullptr, 0, wt_mlp1, mlp_b1, bn1_g, bn1_b, bufA, N_NODES, EP_BN_LRELU, 0);
    gemm_kernel<16><<<gM, blk, 0, stream>>>(bufA, HID, nullptr, 0, wt_mlp2, mlp_b2, bn2_g, bn2_b, bufB, N_NODES, EP_BN_LRELU, 0);
    gemm_kernel<16><<<gM, blk, 0, stream>>>(bufB, HID, nullptr, 0, wt_mlp3, mlp_b3, nullptr, nullptr, x_mlp, N_NODES, EP_BIAS, 0);
    hipMemcpyAsync(g, x_mlp, (size_t)N_NODES * HID * 4, hipMemcpyDeviceToDevice, stream);

    // ---- GAT layers ----
    for (int i = 0; i < 4; ++i) {
        gemm_kernel<16><<<gM, blk, 0, stream>>>(g, HID, nullptr, 0, wt_gl[i],
                                                gat_bl + i * HID, nullptr, nullptr, bufA16, N_NODES, EP_BIAS, 1);
        gemm_kernel<16><<<gM, blk, 0, stream>>>(g, HID, nullptr, 0, wt_gr[i],
                                                gat_br + i * HID, nullptr, nullptr, bufB16, N_NODES, EP_BIAS, 1);
        gat_agg_kernel<<<N_NODES, dim3(128), 0, stream>>>(bufA16, bufB16, g, off, csr,
                                                          gat_att + i * HID, gat_bias + i * HID,
                                                          ln_g + i * HID, ln_b + i * HID);
    }

    // ---- regression head ----
    gemm_kernel<16><<<gM, blk, 0, stream>>>(x_mlp, HID, g, HID, wt_h1, head_b1, hbn1_g, hbn1_b, bufA, N_NODES, EP_BN_LRELU, 0);
    gemm_kernel<8><<<gM, blk, 0, stream>>>(bufA, HID, nullptr, 0, wt_h2, head_b2, hbn2_g, hbn2_b, bufB, N_NODES, EP_BN_LRELU, 0);
    gemm_kernel<4><<<gM, blk, 0, stream>>>(bufB, HID / 2, nullptr, 0, wt_h3, head_b3, nullptr, nullptr, bufA, N_NODES, EP_LRELU, 0);
    head_final_kernel<<<(N_NODES + 3) / 4, blk, 0, stream>>>(bufA, head_w4, head_b4, out);
}

// Round 6
// 979.618 us; speedup vs baseline: 1.7565x; 1.0007x over previous
//
#include <hip/hip_runtime.h>
#include <hip/hip_bf16.h>

#define N_NODES 20000
#define E_EDGES 320000
#define E_TOT   (E_EDGES + N_NODES)
#define IN_CH   128
#define HID     256
#define HEADS   8
#define CPH     32

enum { EP_BIAS = 0, EP_BN_LRELU = 1, EP_LRELU = 2 };

typedef _Float16 f16;
typedef f16  f16x4 __attribute__((ext_vector_type(4)));
typedef f16  f16x8 __attribute__((ext_vector_type(8)));
typedef float f32x4 __attribute__((ext_vector_type(4)));

// ---------------- weight prep: fp32 [K,Nc] -> fp16 fragment-major ----------------
// Fragment order: [kb][ks][ct][lane][8 f16]; element (i):
//   e=i&7, l=(i>>3)&63, r=i>>9, ct=r%NT, q=r/NT, ks=q&1, kb=q>>1
//   n = ct*16 + (l&15);  k = kb*64 + ks*32 + ((l>>4)<<3) + e;  dst[i] = W[k][n]
struct WDesc { const float* src; f16* dst; int K; int Nc; int NT; };
struct WDescs { WDesc d[14]; };

__global__ __launch_bounds__(256)
void wprep_kernel(WDescs ds) {
    WDesc w = ds.d[blockIdx.y];
    int total = w.K * w.Nc;
    int i = blockIdx.x * 256 + threadIdx.x;
    if (i < total) {
        int e  = i & 7;
        int l  = (i >> 3) & 63;
        int r  = i >> 9;
        int ct = r % w.NT;
        int q  = r / w.NT;
        int ks = q & 1;
        int kb = q >> 1;
        int n  = ct * 16 + (l & 15);
        int k  = kb * 64 + ks * 32 + ((l >> 4) << 3) + e;
        w.dst[i] = (f16)w.src[(size_t)k * w.Nc + n];
    }
}

// ---------------- barrier-free fp16 MFMA GEMM: C = epilogue(A@W + b) ----------------
// A fp32 [M,K1] (+ optional A2 [M,K2] concat along K), Wf fragment-major f16.
// Block = 4 waves x 16 rows = 64 rows; each wave computes 16 x (NT*16) outputs.
template<int NT>
__global__ __launch_bounds__(256)
void gemm_kernel(const float* __restrict__ A1, int K1,
                 const float* __restrict__ A2, int K2,
                 const f16* __restrict__ Wf,
                 const float* __restrict__ bias,
                 const float* __restrict__ bng,
                 const float* __restrict__ bnb,
                 void* __restrict__ Cout,
                 int M, int mode, int f16out)
{
    const int Nc = NT * 16;
    const int K = K1 + K2;
    const int tid  = threadIdx.x;
    const int wave = tid >> 6;
    const int lane = tid & 63;
    const int quad = lane >> 4;
    const int bm = blockIdx.x * 64;

    // A-operand row for this lane (m = lane&15), clamped for the M-tail
    int rowA = bm + wave * 16 + (lane & 15);
    if (rowA >= M) rowA = M - 1;

    f32x4 acc[NT];
#pragma unroll
    for (int j = 0; j < NT; ++j) acc[j] = (f32x4){0.f, 0.f, 0.f, 0.f};

    const int KB = K >> 6;
#pragma unroll 2
    for (int kb = 0; kb < KB; ++kb) {
#pragma unroll
        for (int ks = 0; ks < 2; ++ks) {
            int k = kb * 64 + ks * 32 + quad * 8;
            const float* ap = (k < K1) ? &A1[(size_t)rowA * K1 + k]
                                       : &A2[(size_t)rowA * K2 + (k - K1)];
            float4 p0 = *(const float4*)ap;
            float4 p1 = *(const float4*)(ap + 4);
            f16x8 a;
            a[0] = (f16)p0.x; a[1] = (f16)p0.y; a[2] = (f16)p0.z; a[3] = (f16)p0.w;
            a[4] = (f16)p1.x; a[5] = (f16)p1.y; a[6] = (f16)p1.z; a[7] = (f16)p1.w;
            const f16* bp = Wf + (((size_t)(kb * 2 + ks) * NT) << 9) + lane * 8;
#pragma unroll
            for (int ct = 0; ct < NT; ++ct) {
                f16x8 b = *(const f16x8*)(bp + ((size_t)ct << 9));
                acc[ct] = __builtin_amdgcn_mfma_f32_16x16x32_f16(a, b, acc[ct], 0, 0, 0);
            }
        }
    }

    // epilogue: C/D layout col=lane&15, row=quad*4+reg
    const int r0 = bm + wave * 16 + (quad << 2);
    const int c0 = lane & 15;
#pragma unroll
    for (int ct = 0; ct < NT; ++ct) {
        int col = c0 + ct * 16;
        float bv = bias[col];
        float sc = 1.f, sh = 0.f;
        if (mode == EP_BN_LRELU) {
            sc = bng[col] * rsqrtf(1.f + 1e-5f);
            sh = bnb[col];
        }
#pragma unroll
        for (int reg = 0; reg < 4; ++reg) {
            int row = r0 + reg;
            if (row < M) {
                float v = acc[ct][reg] + bv;
                if (mode == EP_BN_LRELU) { v = v * sc + sh; v = v > 0.f ? v : 0.1f * v; }
                else if (mode == EP_LRELU) { v = v > 0.f ? v : 0.1f * v; }
                if (f16out) ((f16*)Cout)[(size_t)row * Nc + col] = (f16)v;
                else        ((float*)Cout)[(size_t)row * Nc + col] = v;
            }
        }
    }
}

// ---------------- CSR build ----------------
__global__ void deg_init_kernel(int* __restrict__ cnt) {
    int i = blockIdx.x * 256 + threadIdx.x;
    if (i < N_NODES) cnt[i] = 1;   // self loop
}
__global__ void deg_count_kernel(const int* __restrict__ dst, int* __restrict__ cnt) {
    int e = blockIdx.x * 256 + threadIdx.x;
    if (e < E_EDGES) atomicAdd(&cnt[dst[e]], 1);
}
__global__ __launch_bounds__(1024)
void scan_kernel(const int* __restrict__ cnt, int* __restrict__ off) {
    __shared__ int lds[1024];
    __shared__ int carry;
    int tid = threadIdx.x;
    if (tid == 0) carry = 0;
    __syncthreads();
    for (int base = 0; base < N_NODES; base += 1024) {
        int i = base + tid;
        int v = (i < N_NODES) ? cnt[i] : 0;
        lds[tid] = v;
        __syncthreads();
        for (int st = 1; st < 1024; st <<= 1) {
            int a = (tid >= st) ? lds[tid - st] : 0;
            __syncthreads();
            lds[tid] += a;
            __syncthreads();
        }
        if (i < N_NODES) off[i] = carry + lds[tid] - v;
        __syncthreads();
        if (tid == 1023) carry += lds[1023];
        __syncthreads();
    }
    if (tid == 0) off[N_NODES] = carry;
}
__global__ void self_fill_kernel(const int* __restrict__ off, int* __restrict__ fill, int* __restrict__ csr) {
    int i = blockIdx.x * 256 + threadIdx.x;
    if (i < N_NODES) { csr[off[i]] = i; fill[i] = 1; }
}
__global__ void edge_fill_kernel(const int* __restrict__ src, const int* __restrict__ dst,
                                 const int* __restrict__ off, int* __restrict__ fill, int* __restrict__ csr) {
    int e = blockIdx.x * 256 + threadIdx.x;
    if (e < E_EDGES) {
        int d = dst[e];
        int pos = atomicAdd(&fill[d], 1);
        csr[off[d] + pos] = src[e];
    }
}

// ---------------- fused GATv2 aggregation: 1 wave/node, 4 ch/thread ----------------
__global__ __launch_bounds__(256)
void gat_agg_kernel(const f16* __restrict__ xl, const f16* __restrict__ xr,
                    float* __restrict__ g,
                    const int* __restrict__ off, const int* __restrict__ csr,
                    const float* __restrict__ att,
                    const float* __restrict__ bias,
                    const float* __restrict__ lng,
                    const float* __restrict__ lnb)
{
    const int wv = threadIdx.x >> 6;
    const int ln = threadIdx.x & 63;           // channels 4ln..4ln+3; head = ln>>3
    const int n  = blockIdx.x * 4 + wv;
    if (n >= N_NODES) return;

    const f16x4* xl4 = (const f16x4*)xl;
    f16x4 xrv = ((const f16x4*)xr)[(size_t)n * 64 + ln];
    float xr0 = (float)xrv[0], xr1 = (float)xrv[1], xr2 = (float)xrv[2], xr3 = (float)xrv[3];
    float4 av = ((const float4*)att)[ln];

    float s = 0.f, o0 = 0.f, o1 = 0.f, o2 = 0.f, o3 = 0.f;

    auto proc = [&](f16x4 xv) {
        float x0 = (float)xv[0], x1 = (float)xv[1], x2 = (float)xv[2], x3 = (float)xv[3];
        float v0 = x0 + xr0; v0 = v0 > 0.f ? v0 : 0.2f * v0;
        float v1 = x1 + xr1; v1 = v1 > 0.f ? v1 : 0.2f * v1;
        float v2 = x2 + xr2; v2 = v2 > 0.f ? v2 : 0.2f * v2;
        float v3 = x3 + xr3; v3 = v3 > 0.f ? v3 : 0.2f * v3;
        float pr = av.x * v0 + av.y * v1 + av.z * v2 + av.w * v3;
        pr += __shfl_xor(pr, 4, 8);
        pr += __shfl_xor(pr, 2, 8);
        pr += __shfl_xor(pr, 1, 8);            // per-head logit (8 lanes = 32 ch)
        float e = __expf(pr);                   // logits bounded (|att|~small): no max needed
        s += e;
        o0 += e * x0; o1 += e * x1; o2 += e * x2; o3 += e * x3;
    };

    int p = off[n], end = off[n + 1];
    for (; p + 2 <= end; p += 2) {
        int sA = csr[p], sB = csr[p + 1];
        f16x4 xa = xl4[(size_t)sA * 64 + ln];
        f16x4 xb = xl4[(size_t)sB * 64 + ln];
        proc(xa);
        proc(xb);
    }
    if (p < end) {
        f16x4 xa = xl4[(size_t)csr[p] * 64 + ln];
        proc(xa);
    }

    float inv = 1.f / (s + 1e-16f);
    float4 bi = ((const float4*)bias)[ln];
    float y0 = o0 * inv + bi.x;
    float y1 = o1 * inv + bi.y;
    float y2 = o2 * inv + bi.z;
    float y3 = o3 * inv + bi.w;

    // LayerNorm over 256 channels, pure wave-shuffle
    float s1 = y0 + y1 + y2 + y3;
    float s2 = y0 * y0 + y1 * y1 + y2 * y2 + y3 * y3;
#pragma unroll
    for (int d = 32; d; d >>= 1) { s1 += __shfl_xor(s1, d, 64); s2 += __shfl_xor(s2, d, 64); }
    float mu  = s1 * (1.f / HID);
    float ex2 = s2 * (1.f / HID);
    float rstd = rsqrtf(ex2 - mu * mu + 1e-5f);
    float4 lg = ((const float4*)lng)[ln];
    float4 lb = ((const float4*)lnb)[ln];
    float nv0 = (y0 - mu) * rstd * lg.x + lb.x; nv0 = nv0 > 0.f ? nv0 : 0.1f * nv0;
    float nv1 = (y1 - mu) * rstd * lg.y + lb.y; nv1 = nv1 > 0.f ? nv1 : 0.1f * nv1;
    float nv2 = (y2 - mu) * rstd * lg.z + lb.z; nv2 = nv2 > 0.f ? nv2 : 0.1f * nv2;
    float nv3 = (y3 - mu) * rstd * lg.w + lb.w; nv3 = nv3 > 0.f ? nv3 : 0.1f * nv3;

    float4 gv = ((const float4*)g)[(size_t)n * 64 + ln];
    ((float4*)g)[(size_t)n * 64 + ln] = make_float4(nv0 + gv.x, nv1 + gv.y, nv2 + gv.z, nv3 + gv.w);
}

// ---------------- final head dot: [N,64] @ [64,1] + b ----------------
__global__ __launch_bounds__(256)
void head_final_kernel(const float* __restrict__ t3, const float* __restrict__ w4,
                       const float* __restrict__ b4, float* __restrict__ out)
{
    int row = blockIdx.x * 4 + (threadIdx.x >> 6);
    int lane = threadIdx.x & 63;
    float v = 0.f;
    if (row < N_NODES) v = t3[(size_t)row * 64 + lane] * w4[lane];
#pragma unroll
    for (int d = 32; d; d >>= 1) v += __shfl_xor(v, d, 64);
    if (row < N_NODES && lane == 0) out[row] = v + b4[0];
}

static inline size_t align_up(size_t v, size_t a) { return (v + a - 1) & ~(a - 1); }

extern "C" void kernel_launch(void* const* d_in, const int* in_sizes, int n_in,
                              void* d_out, int out_size, void* d_ws, size_t ws_size,
                              hipStream_t stream)
{
    const float* x      = (const float*)d_in[0];
    const int*   ei     = (const int*)d_in[1];
    const float* mlp_w1 = (const float*)d_in[2];
    const float* mlp_b1 = (const float*)d_in[3];
    const float* bn1_g  = (const float*)d_in[4];
    const float* bn1_b  = (const float*)d_in[5];
    const float* mlp_w2 = (const float*)d_in[6];
    const float* mlp_b2 = (const float*)d_in[7];
    const float* bn2_g  = (const float*)d_in[8];
    const float* bn2_b  = (const float*)d_in[9];
    const float* mlp_w3 = (const float*)d_in[10];
    const float* mlp_b3 = (const float*)d_in[11];
    const float* gat_wl = (const float*)d_in[12];
    const float* gat_bl = (const float*)d_in[13];
    const float* gat_wr = (const float*)d_in[14];
    const float* gat_br = (const float*)d_in[15];
    const float* gat_att  = (const float*)d_in[16];
    const float* gat_bias = (const float*)d_in[17];
    const float* ln_g   = (const float*)d_in[18];
    const float* ln_b   = (const float*)d_in[19];
    const float* head_w1 = (const float*)d_in[20];
    const float* head_b1 = (const float*)d_in[21];
    const float* hbn1_g  = (const float*)d_in[22];
    const float* hbn1_b  = (const float*)d_in[23];
    const float* head_w2 = (const float*)d_in[24];
    const float* head_b2 = (const float*)d_in[25];
    const float* hbn2_g  = (const float*)d_in[26];
    const float* hbn2_b  = (const float*)d_in[27];
    const float* head_w3 = (const float*)d_in[28];
    const float* head_b3 = (const float*)d_in[29];
    const float* head_w4 = (const float*)d_in[30];
    const float* head_b4 = (const float*)d_in[31];
    float* out = (float*)d_out;

    // ---- workspace layout ----
    char* w = (char*)d_ws;
    size_t p = 0;
    int* off  = (int*)(w + p); p = align_up(p + (N_NODES + 1) * sizeof(int), 64);
    int* fill = (int*)(w + p); p = align_up(p + N_NODES * sizeof(int), 64);
    int* csr  = (int*)(w + p); p = align_up(p + E_TOT * sizeof(int), 64);
    float* bufA  = (float*)(w + p); p = align_up(p + (size_t)N_NODES * HID * 4, 64);
    float* bufB  = (float*)(w + p); p = align_up(p + (size_t)N_NODES * HID * 4, 64);
    float* x_mlp = (float*)(w + p); p = align_up(p + (size_t)N_NODES * HID * 4, 64);
    float* g     = (float*)(w + p); p = align_up(p + (size_t)N_NODES * HID * 4, 64);
    f16* bufA16 = (f16*)(w + p); p = align_up(p + (size_t)N_NODES * HID * 2, 64);
    f16* bufB16 = (f16*)(w + p); p = align_up(p + (size_t)N_NODES * HID * 2, 64);
    auto walloc = [&](size_t elems) {
        f16* q = (f16*)(w + p);
        p = align_up(p + elems * 2, 1024);
        return q;
    };
    f16* wt_mlp1 = walloc((size_t)IN_CH * HID);
    f16* wt_mlp2 = walloc((size_t)HID * HID);
    f16* wt_mlp3 = walloc((size_t)HID * HID);
    f16 *wt_gl[4], *wt_gr[4];
    for (int i = 0; i < 4; ++i) {
        wt_gl[i] = walloc((size_t)HID * HID);
        wt_gr[i] = walloc((size_t)HID * HID);
    }
    f16* wt_h1 = walloc((size_t)2 * HID * HID);
    f16* wt_h2 = walloc((size_t)HID * (HID / 2));
    f16* wt_h3 = walloc((size_t)(HID / 2) * (HID / 4));
    (void)ws_size; (void)in_sizes; (void)n_in; (void)out_size;

    const int* e_src = ei;
    const int* e_dst = ei + E_EDGES;

    dim3 blk(256);
    dim3 gM((N_NODES + 63) / 64);      // 313

    // ---- weight prep (fp32 -> fp16 fragment-major) ----
    WDescs ds;
    ds.d[0]  = { mlp_w1, wt_mlp1, IN_CH, HID, 16 };
    ds.d[1]  = { mlp_w2, wt_mlp2, HID, HID, 16 };
    ds.d[2]  = { mlp_w3, wt_mlp3, HID, HID, 16 };
    for (int i = 0; i < 4; ++i) {
        ds.d[3 + i] = { gat_wl + (size_t)i * HID * HID, wt_gl[i], HID, HID, 16 };
        ds.d[7 + i] = { gat_wr + (size_t)i * HID * HID, wt_gr[i], HID, HID, 16 };
    }
    ds.d[11] = { head_w1, wt_h1, 2 * HID, HID, 16 };
    ds.d[12] = { head_w2, wt_h2, HID, HID / 2, 8 };
    ds.d[13] = { head_w3, wt_h3, HID / 2, HID / 4, 4 };
    {
        dim3 gp((2 * HID * HID + 255) / 256, 14);
        wprep_kernel<<<gp, blk, 0, stream>>>(ds);
    }

    // ---- CSR by destination ----
    deg_init_kernel<<<(N_NODES + 255) / 256, blk, 0, stream>>>(fill);
    deg_count_kernel<<<(E_EDGES + 255) / 256, blk, 0, stream>>>(e_dst, fill);
    scan_kernel<<<1, 1024, 0, stream>>>(fill, off);
    self_fill_kernel<<<(N_NODES + 255) / 256, blk, 0, stream>>>(off, fill, csr);
    edge_fill_kernel<<<(E_EDGES + 255) / 256, blk, 0, stream>>>(e_src, e_dst, off, fill, csr);

    // ---- MLP stem ----
    gemm_kernel<16><<<gM, blk, 0, stream>>>(x, IN_CH, nullptr, 0, wt_mlp1, mlp_b1, bn1_g, bn1_b, bufA, N_NODES, EP_BN_LRELU, 0);
    gemm_kernel<16><<<gM, blk, 0, stream>>>(bufA, HID, nullptr, 0, wt_mlp2, mlp_b2, bn2_g, bn2_b, bufB, N_NODES, EP_BN_LRELU, 0);
    gemm_kernel<16><<<gM, blk, 0, stream>>>(bufB, HID, nullptr, 0, wt_mlp3, mlp_b3, nullptr, nullptr, x_mlp, N_NODES, EP_BIAS, 0);
    hipMemcpyAsync(g, x_mlp, (size_t)N_NODES * HID * 4, hipMemcpyDeviceToDevice, stream);

    // ---- GAT layers ----
    for (int i = 0; i < 4; ++i) {
        gemm_kernel<16><<<gM, blk, 0, stream>>>(g, HID, nullptr, 0, wt_gl[i],
                                                gat_bl + i * HID, nullptr, nullptr, bufA16, N_NODES, EP_BIAS, 1);
        gemm_kernel<16><<<gM, blk, 0, stream>>>(g, HID, nullptr, 0, wt_gr[i],
                                                gat_br + i * HID, nullptr, nullptr, bufB16, N_NODES, EP_BIAS, 1);
        gat_agg_kernel<<<(N_NODES + 3) / 4, blk, 0, stream>>>(bufA16, bufB16, g, off, csr,
                                                              gat_att + i * HID, gat_bias + i * HID,
                                                              ln_g + i * HID, ln_b + i * HID);
    }

    // ---- regression head ----
    gemm_kernel<16><<<gM, blk, 0, stream>>>(x_mlp, HID, g, HID, wt_h1, head_b1, hbn1_g, hbn1_b, bufA, N_NODES, EP_BN_LRELU, 0);
    gemm_kernel<8><<<gM, blk, 0, stream>>>(bufA, HID, nullptr, 0, wt_h2, head_b2, hbn2_g, hbn2_b, bufB, N_NODES, EP_BN_LRELU, 0);
    gemm_kernel<4><<<gM, blk, 0, stream>>>(bufB, HID / 2, nullptr, 0, wt_h3, head_b3, nullptr, nullptr, bufA, N_NODES, EP_LRELU, 0);
    head_final_kernel<<<(N_NODES + 3) / 4, blk, 0, stream>>>(bufA, head_w4, head_b4, out);
}

// Round 7
// 602.592 us; speedup vs baseline: 2.8556x; 1.6257x over previous
//
#include <hip/hip_runtime.h>
#include <hip/hip_bf16.h>

#define N_NODES 20000
#define E_EDGES 320000
#define E_TOT   (E_EDGES + N_NODES)
#define IN_CH   128
#define HID     256
#define HEADS   8
#define CPH     32

enum { EP_BIAS = 0, EP_BN_LRELU = 1, EP_LRELU = 2 };

typedef _Float16 f16;
typedef f16  f16x4 __attribute__((ext_vector_type(4)));
typedef f16  f16x8 __attribute__((ext_vector_type(8)));
typedef float f32x4 __attribute__((ext_vector_type(4)));

// ---------------- weight prep: fp32 [K,Nc] -> fp16 fragment-major ----------------
// Fragment stream: [kb][ks][ct_global][lane][8 f16], ct_global = ct0 + ct_local,
// NTOT = total col-tiles of the (possibly fused) destination buffer.
struct WDesc { const float* src; f16* dst; int K; int Nc; int NTOT; int ct0; };
struct WDescs { WDesc d[14]; };

__global__ __launch_bounds__(256)
void wprep_kernel(WDescs ds) {
    WDesc w = ds.d[blockIdx.y];
    int total = w.K * w.Nc;
    int i = blockIdx.x * 256 + threadIdx.x;
    if (i < total) {
        int NT_local = w.Nc >> 4;
        int e  = i & 7;
        int l  = (i >> 3) & 63;
        int r  = i >> 9;
        int ct = r % NT_local;
        int q  = r / NT_local;
        int ks = q & 1;
        int kb = q >> 1;
        int n  = ct * 16 + (l & 15);
        int k  = kb * 64 + ks * 32 + ((l >> 4) << 3) + e;
        size_t di = (((size_t)(kb * 2 + ks) * w.NTOT + w.ct0 + ct) << 9) + (l << 3) + e;
        w.dst[di] = (f16)w.src[(size_t)k * w.Nc + n];
    }
}

// ---------------- barrier-free fp16 MFMA GEMM, N-split waves ----------------
// Block = 16 rows; 4 waves split NTOT col-tiles (NT each). Optional dual output:
// cols < NcA -> CoutA (biasA), cols >= NcA -> CoutB (biasB). Grid = ceil(M/16).
template<int NT, int NTOT>
__global__ __launch_bounds__(256)
void gemm_kernel(const float* __restrict__ A1, int K1,
                 const float* __restrict__ A2, int K2,
                 const f16* __restrict__ Wf,
                 const float* __restrict__ biasA,
                 const float* __restrict__ biasB,
                 const float* __restrict__ bng,
                 const float* __restrict__ bnb,
                 void* __restrict__ CoutA,
                 void* __restrict__ CoutB,
                 int NcA, int M, int mode, int f16out)
{
    const int K = K1 + K2;
    const int tid  = threadIdx.x;
    const int wave = tid >> 6;
    const int lane = tid & 63;
    const int quad = lane >> 4;
    const int bm = blockIdx.x * 16;

    int rowA = bm + (lane & 15);
    if (rowA >= M) rowA = M - 1;

    f32x4 acc[NT];
#pragma unroll
    for (int j = 0; j < NT; ++j) acc[j] = (f32x4){0.f, 0.f, 0.f, 0.f};

    const int KB = K >> 6;
#pragma unroll 2
    for (int kb = 0; kb < KB; ++kb) {
#pragma unroll
        for (int ks = 0; ks < 2; ++ks) {
            int k = kb * 64 + ks * 32 + quad * 8;
            const float* ap = (k < K1) ? &A1[(size_t)rowA * K1 + k]
                                       : &A2[(size_t)rowA * K2 + (k - K1)];
            float4 p0 = *(const float4*)ap;
            float4 p1 = *(const float4*)(ap + 4);
            f16x8 a;
            a[0] = (f16)p0.x; a[1] = (f16)p0.y; a[2] = (f16)p0.z; a[3] = (f16)p0.w;
            a[4] = (f16)p1.x; a[5] = (f16)p1.y; a[6] = (f16)p1.z; a[7] = (f16)p1.w;
            const f16* bp = Wf + (((size_t)(kb * 2 + ks) * NTOT + wave * NT) << 9) + lane * 8;
#pragma unroll
            for (int ct = 0; ct < NT; ++ct) {
                f16x8 b = *(const f16x8*)(bp + ((size_t)ct << 9));
                acc[ct] = __builtin_amdgcn_mfma_f32_16x16x32_f16(a, b, acc[ct], 0, 0, 0);
            }
        }
    }

    // epilogue: C/D layout col=lane&15, row=quad*4+reg
    const int r0 = bm + (quad << 2);
    const int c0 = lane & 15;
    const int NcB = NTOT * 16 - NcA;
#pragma unroll
    for (int ct = 0; ct < NT; ++ct) {
        int col = (wave * NT + ct) * 16 + c0;
        bool isB = col >= NcA;
        int colL = isB ? col - NcA : col;
        float bv = isB ? biasB[colL] : biasA[colL];
        float sc = 1.f, sh = 0.f;
        if (mode == EP_BN_LRELU) {
            sc = bng[col] * rsqrtf(1.f + 1e-5f);
            sh = bnb[col];
        }
        void* Cout = isB ? CoutB : CoutA;
        int stride = isB ? NcB : NcA;
#pragma unroll
        for (int reg = 0; reg < 4; ++reg) {
            int row = r0 + reg;
            if (row < M) {
                float v = acc[ct][reg] + bv;
                if (mode == EP_BN_LRELU) { v = v * sc + sh; v = v > 0.f ? v : 0.1f * v; }
                else if (mode == EP_LRELU) { v = v > 0.f ? v : 0.1f * v; }
                if (f16out) ((f16*)Cout)[(size_t)row * stride + colL] = (f16)v;
                else        ((float*)Cout)[(size_t)row * stride + colL] = v;
            }
        }
    }
}

// ---------------- CSR build ----------------
__global__ void deg_init_kernel(int* __restrict__ cnt) {
    int i = blockIdx.x * 256 + threadIdx.x;
    if (i < N_NODES) cnt[i] = 1;   // self loop
}
__global__ void deg_count_kernel(const int* __restrict__ dst, int* __restrict__ cnt) {
    int e = blockIdx.x * 256 + threadIdx.x;
    if (e < E_EDGES) atomicAdd(&cnt[dst[e]], 1);
}
__global__ __launch_bounds__(1024)
void scan_kernel(const int* __restrict__ cnt, int* __restrict__ off) {
    __shared__ int lds[1024];
    __shared__ int carry;
    int tid = threadIdx.x;
    if (tid == 0) carry = 0;
    __syncthreads();
    for (int base = 0; base < N_NODES; base += 1024) {
        int i = base + tid;
        int v = (i < N_NODES) ? cnt[i] : 0;
        lds[tid] = v;
        __syncthreads();
        for (int st = 1; st < 1024; st <<= 1) {
            int a = (tid >= st) ? lds[tid - st] : 0;
            __syncthreads();
            lds[tid] += a;
            __syncthreads();
        }
        if (i < N_NODES) off[i] = carry + lds[tid] - v;
        __syncthreads();
        if (tid == 1023) carry += lds[1023];
        __syncthreads();
    }
    if (tid == 0) off[N_NODES] = carry;
}
__global__ void self_fill_kernel(const int* __restrict__ off, int* __restrict__ fill, int* __restrict__ csr) {
    int i = blockIdx.x * 256 + threadIdx.x;
    if (i < N_NODES) { csr[off[i]] = i; fill[i] = 1; }
}
__global__ void edge_fill_kernel(const int* __restrict__ src, const int* __restrict__ dst,
                                 const int* __restrict__ off, int* __restrict__ fill, int* __restrict__ csr) {
    int e = blockIdx.x * 256 + threadIdx.x;
    if (e < E_EDGES) {
        int d = dst[e];
        int pos = atomicAdd(&fill[d], 1);
        csr[off[d] + pos] = src[e];
    }
}

// ---------------- fused GATv2 aggregation: 1 wave/node, 4 ch/thread ----------------
__global__ __launch_bounds__(256)
void gat_agg_kernel(const f16* __restrict__ xl, const f16* __restrict__ xr,
                    float* __restrict__ g,
                    const int* __restrict__ off, const int* __restrict__ csr,
                    const float* __restrict__ att,
                    const float* __restrict__ bias,
                    const float* __restrict__ lng,
                    const float* __restrict__ lnb)
{
    const int wv = threadIdx.x >> 6;
    const int ln = threadIdx.x & 63;           // channels 4ln..4ln+3; head = ln>>3
    const int n  = blockIdx.x * 4 + wv;
    if (n >= N_NODES) return;

    const f16x4* xl4 = (const f16x4*)xl;
    f16x4 xrv = ((const f16x4*)xr)[(size_t)n * 64 + ln];
    float xr0 = (float)xrv[0], xr1 = (float)xrv[1], xr2 = (float)xrv[2], xr3 = (float)xrv[3];
    float4 av = ((const float4*)att)[ln];

    float s = 0.f, o0 = 0.f, o1 = 0.f, o2 = 0.f, o3 = 0.f;

    auto proc = [&](f16x4 xv) {
        float x0 = (float)xv[0], x1 = (float)xv[1], x2 = (float)xv[2], x3 = (float)xv[3];
        float v0 = x0 + xr0; v0 = v0 > 0.f ? v0 : 0.2f * v0;
        float v1 = x1 + xr1; v1 = v1 > 0.f ? v1 : 0.2f * v1;
        float v2 = x2 + xr2; v2 = v2 > 0.f ? v2 : 0.2f * v2;
        float v3 = x3 + xr3; v3 = v3 > 0.f ? v3 : 0.2f * v3;
        float pr = av.x * v0 + av.y * v1 + av.z * v2 + av.w * v3;
        pr += __shfl_xor(pr, 4, 8);
        pr += __shfl_xor(pr, 2, 8);
        pr += __shfl_xor(pr, 1, 8);            // per-head logit (8 lanes = 32 ch)
        float e = __expf(pr);                   // logits bounded: no running max needed
        s += e;
        o0 += e * x0; o1 += e * x1; o2 += e * x2; o3 += e * x3;
    };

    int p = off[n], end = off[n + 1];
    for (; p + 2 <= end; p += 2) {
        int sA = csr[p], sB = csr[p + 1];
        f16x4 xa = xl4[(size_t)sA * 64 + ln];
        f16x4 xb = xl4[(size_t)sB * 64 + ln];
        proc(xa);
        proc(xb);
    }
    if (p < end) {
        f16x4 xa = xl4[(size_t)csr[p] * 64 + ln];
        proc(xa);
    }

    float inv = 1.f / (s + 1e-16f);
    float4 bi = ((const float4*)bias)[ln];
    float y0 = o0 * inv + bi.x;
    float y1 = o1 * inv + bi.y;
    float y2 = o2 * inv + bi.z;
    float y3 = o3 * inv + bi.w;

    // LayerNorm over 256 channels, pure wave-shuffle
    float s1 = y0 + y1 + y2 + y3;
    float s2 = y0 * y0 + y1 * y1 + y2 * y2 + y3 * y3;
#pragma unroll
    for (int d = 32; d; d >>= 1) { s1 += __shfl_xor(s1, d, 64); s2 += __shfl_xor(s2, d, 64); }
    float mu  = s1 * (1.f / HID);
    float ex2 = s2 * (1.f / HID);
    float rstd = rsqrtf(ex2 - mu * mu + 1e-5f);
    float4 lg = ((const float4*)lng)[ln];
    float4 lb = ((const float4*)lnb)[ln];
    float nv0 = (y0 - mu) * rstd * lg.x + lb.x; nv0 = nv0 > 0.f ? nv0 : 0.1f * nv0;
    float nv1 = (y1 - mu) * rstd * lg.y + lb.y; nv1 = nv1 > 0.f ? nv1 : 0.1f * nv1;
    float nv2 = (y2 - mu) * rstd * lg.z + lb.z; nv2 = nv2 > 0.f ? nv2 : 0.1f * nv2;
    float nv3 = (y3 - mu) * rstd * lg.w + lb.w; nv3 = nv3 > 0.f ? nv3 : 0.1f * nv3;

    float4 gv = ((const float4*)g)[(size_t)n * 64 + ln];
    ((float4*)g)[(size_t)n * 64 + ln] = make_float4(nv0 + gv.x, nv1 + gv.y, nv2 + gv.z, nv3 + gv.w);
}

// ---------------- final head dot: [N,64] @ [64,1] + b ----------------
__global__ __launch_bounds__(256)
void head_final_kernel(const float* __restrict__ t3, const float* __restrict__ w4,
                       const float* __restrict__ b4, float* __restrict__ out)
{
    int row = blockIdx.x * 4 + (threadIdx.x >> 6);
    int lane = threadIdx.x & 63;
    float v = 0.f;
    if (row < N_NODES) v = t3[(size_t)row * 64 + lane] * w4[lane];
#pragma unroll
    for (int d = 32; d; d >>= 1) v += __shfl_xor(v, d, 64);
    if (row < N_NODES && lane == 0) out[row] = v + b4[0];
}

static inline size_t align_up(size_t v, size_t a) { return (v + a - 1) & ~(a - 1); }

extern "C" void kernel_launch(void* const* d_in, const int* in_sizes, int n_in,
                              void* d_out, int out_size, void* d_ws, size_t ws_size,
                              hipStream_t stream)
{
    const float* x      = (const float*)d_in[0];
    const int*   ei     = (const int*)d_in[1];
    const float* mlp_w1 = (const float*)d_in[2];
    const float* mlp_b1 = (const float*)d_in[3];
    const float* bn1_g  = (const float*)d_in[4];
    const float* bn1_b  = (const float*)d_in[5];
    const float* mlp_w2 = (const float*)d_in[6];
    const float* mlp_b2 = (const float*)d_in[7];
    const float* bn2_g  = (const float*)d_in[8];
    const float* bn2_b  = (const float*)d_in[9];
    const float* mlp_w3 = (const float*)d_in[10];
    const float* mlp_b3 = (const float*)d_in[11];
    const float* gat_wl = (const float*)d_in[12];
    const float* gat_bl = (const float*)d_in[13];
    const float* gat_wr = (const float*)d_in[14];
    const float* gat_br = (const float*)d_in[15];
    const float* gat_att  = (const float*)d_in[16];
    const float* gat_bias = (const float*)d_in[17];
    const float* ln_g   = (const float*)d_in[18];
    const float* ln_b   = (const float*)d_in[19];
    const float* head_w1 = (const float*)d_in[20];
    const float* head_b1 = (const float*)d_in[21];
    const float* hbn1_g  = (const float*)d_in[22];
    const float* hbn1_b  = (const float*)d_in[23];
    const float* head_w2 = (const float*)d_in[24];
    const float* head_b2 = (const float*)d_in[25];
    const float* hbn2_g  = (const float*)d_in[26];
    const float* hbn2_b  = (const float*)d_in[27];
    const float* head_w3 = (const float*)d_in[28];
    const float* head_b3 = (const float*)d_in[29];
    const float* head_w4 = (const float*)d_in[30];
    const float* head_b4 = (const float*)d_in[31];
    float* out = (float*)d_out;

    // ---- workspace layout ----
    char* w = (char*)d_ws;
    size_t p = 0;
    int* off  = (int*)(w + p); p = align_up(p + (N_NODES + 1) * sizeof(int), 64);
    int* fill = (int*)(w + p); p = align_up(p + N_NODES * sizeof(int), 64);
    int* csr  = (int*)(w + p); p = align_up(p + E_TOT * sizeof(int), 64);
    float* bufA  = (float*)(w + p); p = align_up(p + (size_t)N_NODES * HID * 4, 64);
    float* bufB  = (float*)(w + p); p = align_up(p + (size_t)N_NODES * HID * 4, 64);
    float* x_mlp = (float*)(w + p); p = align_up(p + (size_t)N_NODES * HID * 4, 64);
    float* g     = (float*)(w + p); p = align_up(p + (size_t)N_NODES * HID * 4, 64);
    f16* bufA16 = (f16*)(w + p); p = align_up(p + (size_t)N_NODES * HID * 2, 64);
    f16* bufB16 = (f16*)(w + p); p = align_up(p + (size_t)N_NODES * HID * 2, 64);
    auto walloc = [&](size_t elems) {
        f16* q = (f16*)(w + p);
        p = align_up(p + elems * 2, 1024);
        return q;
    };
    f16* wt_mlp1 = walloc((size_t)IN_CH * HID);
    f16* wt_mlp2 = walloc((size_t)HID * HID);
    f16* wt_mlp3 = walloc((size_t)HID * HID);
    f16* wt_g[4];                                   // fused wl|wr, Nc_tot = 512
    for (int i = 0; i < 4; ++i) wt_g[i] = walloc((size_t)HID * 2 * HID);
    f16* wt_h1 = walloc((size_t)2 * HID * HID);
    f16* wt_h2 = walloc((size_t)HID * (HID / 2));
    f16* wt_h3 = walloc((size_t)(HID / 2) * (HID / 4));
    (void)ws_size; (void)in_sizes; (void)n_in; (void)out_size;

    const int* e_src = ei;
    const int* e_dst = ei + E_EDGES;

    dim3 blk(256);
    dim3 gM((N_NODES + 15) / 16);      // 1250

    // ---- weight prep (fp32 -> fp16 fragment-major; wl+wr fused per layer) ----
    WDescs ds;
    ds.d[0]  = { mlp_w1, wt_mlp1, IN_CH, HID, 16, 0 };
    ds.d[1]  = { mlp_w2, wt_mlp2, HID, HID, 16, 0 };
    ds.d[2]  = { mlp_w3, wt_mlp3, HID, HID, 16, 0 };
    for (int i = 0; i < 4; ++i) {
        ds.d[3 + 2 * i] = { gat_wl + (size_t)i * HID * HID, wt_g[i], HID, HID, 32, 0 };
        ds.d[4 + 2 * i] = { gat_wr + (size_t)i * HID * HID, wt_g[i], HID, HID, 32, 16 };
    }
    ds.d[11] = { head_w1, wt_h1, 2 * HID, HID, 16, 0 };
    ds.d[12] = { head_w2, wt_h2, HID, HID / 2, 8, 0 };
    ds.d[13] = { head_w3, wt_h3, HID / 2, HID / 4, 4, 0 };
    {
        dim3 gp((2 * HID * HID + 255) / 256, 14);
        wprep_kernel<<<gp, blk, 0, stream>>>(ds);
    }

    // ---- CSR by destination ----
    deg_init_kernel<<<(N_NODES + 255) / 256, blk, 0, stream>>>(fill);
    deg_count_kernel<<<(E_EDGES + 255) / 256, blk, 0, stream>>>(e_dst, fill);
    scan_kernel<<<1, 1024, 0, stream>>>(fill, off);
    self_fill_kernel<<<(N_NODES + 255) / 256, blk, 0, stream>>>(off, fill, csr);
    edge_fill_kernel<<<(E_EDGES + 255) / 256, blk, 0, stream>>>(e_src, e_dst, off, fill, csr);

    // ---- MLP stem ----
    gemm_kernel<4, 16><<<gM, blk, 0, stream>>>(x, IN_CH, nullptr, 0, wt_mlp1, mlp_b1, nullptr,
                                               bn1_g, bn1_b, bufA, nullptr, HID, N_NODES, EP_BN_LRELU, 0);
    gemm_kernel<4, 16><<<gM, blk, 0, stream>>>(bufA, HID, nullptr, 0, wt_mlp2, mlp_b2, nullptr,
                                               bn2_g, bn2_b, bufB, nullptr, HID, N_NODES, EP_BN_LRELU, 0);
    gemm_kernel<4, 16><<<gM, blk, 0, stream>>>(bufB, HID, nullptr, 0, wt_mlp3, mlp_b3, nullptr,
                                               nullptr, nullptr, x_mlp, nullptr, HID, N_NODES, EP_BIAS, 0);
    hipMemcpyAsync(g, x_mlp, (size_t)N_NODES * HID * 4, hipMemcpyDeviceToDevice, stream);

    // ---- GAT layers (fused wl|wr dual-output GEMM + fused aggregation) ----
    for (int i = 0; i < 4; ++i) {
        gemm_kernel<8, 32><<<gM, blk, 0, stream>>>(g, HID, nullptr, 0, wt_g[i],
                                                   gat_bl + i * HID, gat_br + i * HID,
                                                   nullptr, nullptr, bufA16, bufB16, HID, N_NODES, EP_BIAS, 1);
        gat_agg_kernel<<<(N_NODES + 3) / 4, blk, 0, stream>>>(bufA16, bufB16, g, off, csr,
                                                              gat_att + i * HID, gat_bias + i * HID,
                                                              ln_g + i * HID, ln_b + i * HID);
    }

    // ---- regression head ----
    gemm_kernel<4, 16><<<gM, blk, 0, stream>>>(x_mlp, HID, g, HID, wt_h1, head_b1, nullptr,
                                               hbn1_g, hbn1_b, bufA, nullptr, HID, N_NODES, EP_BN_LRELU, 0);
    gemm_kernel<2, 8><<<gM, blk, 0, stream>>>(bufA, HID, nullptr, 0, wt_h2, head_b2, nullptr,
                                              hbn2_g, hbn2_b, bufB, nullptr, HID / 2, N_NODES, EP_BN_LRELU, 0);
    gemm_kernel<1, 4><<<gM, blk, 0, stream>>>(bufB, HID / 2, nullptr, 0, wt_h3, head_b3, nullptr,
                                              nullptr, nullptr, bufA, nullptr, HID / 4, N_NODES, EP_LRELU, 0);
    head_final_kernel<<<(N_NODES + 3) / 4, blk, 0, stream>>>(bufA, head_w4, head_b4, out);
}

// Round 8
// 585.687 us; speedup vs baseline: 2.9380x; 1.0289x over previous
//
#include <hip/hip_runtime.h>
#include <hip/hip_bf16.h>

#define N_NODES 20000
#define E_EDGES 320000
#define E_TOT   (E_EDGES + N_NODES)
#define IN_CH   128
#define HID     256
#define HEADS   8
#define CPH     32

enum { EP_BIAS = 0, EP_BN_LRELU = 1, EP_LRELU = 2 };

typedef _Float16 f16;
typedef f16  f16x4 __attribute__((ext_vector_type(4)));
typedef f16  f16x8 __attribute__((ext_vector_type(8)));
typedef float f32x4 __attribute__((ext_vector_type(4)));

// ---------------- weight prep: fp32 [K,Nc] -> fp16 fragment-major ----------------
// Fragment stream: [kb][ks][ct_global][lane][8 f16], ct_global = ct0 + ct_local.
struct WDesc { const float* src; f16* dst; int K; int Nc; int NTOT; int ct0; };
struct WDescs { WDesc d[14]; };

__global__ __launch_bounds__(256)
void wprep_kernel(WDescs ds) {
    WDesc w = ds.d[blockIdx.y];
    int total = w.K * w.Nc;
    int i = blockIdx.x * 256 + threadIdx.x;
    if (i < total) {
        int NT_local = w.Nc >> 4;
        int e  = i & 7;
        int l  = (i >> 3) & 63;
        int r  = i >> 9;
        int ct = r % NT_local;
        int q  = r / NT_local;
        int ks = q & 1;
        int kb = q >> 1;
        int n  = ct * 16 + (l & 15);
        int k  = kb * 64 + ks * 32 + ((l >> 4) << 3) + e;
        size_t di = (((size_t)(kb * 2 + ks) * w.NTOT + w.ct0 + ct) << 9) + (l << 3) + e;
        w.dst[di] = (f16)w.src[(size_t)k * w.Nc + n];
    }
}

// ---------------- dtype converts ----------------
__global__ void cvt32to16_kernel(const float* __restrict__ in, f16* __restrict__ out, int n) {
    int i = blockIdx.x * 256 + threadIdx.x;
    if (i < n) out[i] = (f16)in[i];
}
__global__ void cvt16to32_kernel(const f16* __restrict__ in, float* __restrict__ out, int n) {
    int i = blockIdx.x * 256 + threadIdx.x;
    if (i < n) out[i] = (float)in[i];
}

// ---------------- barrier-free fp16 MFMA GEMM, N-split waves, f16 activations ----------------
// A1/A2 f16 [M,K1]/[M,K2] concat along K. Block = 16 rows, WAVES waves split NTOT col-tiles.
// Dual output: cols < NcA -> out16A (biasA), cols >= NcA -> out16B (biasB).
template<int NT, int NTOT, int WAVES>
__global__ __launch_bounds__(WAVES * 64)
void gemm_kernel(const f16* __restrict__ A1, int K1,
                 const f16* __restrict__ A2, int K2,
                 const f16* __restrict__ Wf,
                 const float* __restrict__ biasA,
                 const float* __restrict__ biasB,
                 const float* __restrict__ bng,
                 const float* __restrict__ bnb,
                 f16* __restrict__ out16A,
                 f16* __restrict__ out16B,
                 int NcA, int M, int mode)
{
    const int K = K1 + K2;
    const int tid  = threadIdx.x;
    const int wave = tid >> 6;
    const int lane = tid & 63;
    const int quad = lane >> 4;
    const int bm = blockIdx.x * 16;

    int rowA = bm + (lane & 15);
    if (rowA >= M) rowA = M - 1;

    f32x4 acc[NT];
#pragma unroll
    for (int j = 0; j < NT; ++j) acc[j] = (f32x4){0.f, 0.f, 0.f, 0.f};

    const int KB = K >> 6;
#pragma unroll 2
    for (int kb = 0; kb < KB; ++kb) {
#pragma unroll
        for (int ks = 0; ks < 2; ++ks) {
            int k = kb * 64 + ks * 32 + quad * 8;
            const f16* ap = (k < K1) ? &A1[(size_t)rowA * K1 + k]
                                     : &A2[(size_t)rowA * K2 + (k - K1)];
            f16x8 a = *(const f16x8*)ap;
            const f16* bp = Wf + (((size_t)(kb * 2 + ks) * NTOT + wave * NT) << 9) + lane * 8;
#pragma unroll
            for (int ct = 0; ct < NT; ++ct) {
                f16x8 b = *(const f16x8*)(bp + ((size_t)ct << 9));
                acc[ct] = __builtin_amdgcn_mfma_f32_16x16x32_f16(a, b, acc[ct], 0, 0, 0);
            }
        }
    }

    // epilogue: C/D layout col=lane&15, row=quad*4+reg
    const int r0 = bm + (quad << 2);
    const int c0 = lane & 15;
    const int NcB = NTOT * 16 - NcA;
#pragma unroll
    for (int ct = 0; ct < NT; ++ct) {
        int col = (wave * NT + ct) * 16 + c0;
        bool isB = col >= NcA;
        int colL = isB ? col - NcA : col;
        float bv = isB ? biasB[colL] : biasA[colL];
        float sc = 1.f, sh = 0.f;
        if (mode == EP_BN_LRELU) {
            sc = bng[col] * rsqrtf(1.f + 1e-5f);
            sh = bnb[col];
        }
        f16* Cout = isB ? out16B : out16A;
        int stride = isB ? NcB : NcA;
#pragma unroll
        for (int reg = 0; reg < 4; ++reg) {
            int row = r0 + reg;
            if (row < M) {
                float v = acc[ct][reg] + bv;
                if (mode == EP_BN_LRELU) { v = v * sc + sh; v = v > 0.f ? v : 0.1f * v; }
                else if (mode == EP_LRELU) { v = v > 0.f ? v : 0.1f * v; }
                Cout[(size_t)row * stride + colL] = (f16)v;
            }
        }
    }
}

// ---------------- CSR build ----------------
__global__ void deg_init_kernel(int* __restrict__ cnt) {
    int i = blockIdx.x * 256 + threadIdx.x;
    if (i < N_NODES) cnt[i] = 1;   // self loop
}
__global__ void deg_count_kernel(const int* __restrict__ dst, int* __restrict__ cnt) {
    int e = blockIdx.x * 256 + threadIdx.x;
    if (e < E_EDGES) atomicAdd(&cnt[dst[e]], 1);
}
__global__ __launch_bounds__(1024)
void scan_kernel(const int* __restrict__ cnt, int* __restrict__ off) {
    __shared__ int lds[1024];
    __shared__ int carry;
    int tid = threadIdx.x;
    if (tid == 0) carry = 0;
    __syncthreads();
    for (int base = 0; base < N_NODES; base += 1024) {
        int i = base + tid;
        int v = (i < N_NODES) ? cnt[i] : 0;
        lds[tid] = v;
        __syncthreads();
        for (int st = 1; st < 1024; st <<= 1) {
            int a = (tid >= st) ? lds[tid - st] : 0;
            __syncthreads();
            lds[tid] += a;
            __syncthreads();
        }
        if (i < N_NODES) off[i] = carry + lds[tid] - v;
        __syncthreads();
        if (tid == 1023) carry += lds[1023];
        __syncthreads();
    }
    if (tid == 0) off[N_NODES] = carry;
}
__global__ void self_fill_kernel(const int* __restrict__ off, int* __restrict__ fill, int* __restrict__ csr) {
    int i = blockIdx.x * 256 + threadIdx.x;
    if (i < N_NODES) { csr[off[i]] = i; fill[i] = 1; }
}
__global__ void edge_fill_kernel(const int* __restrict__ src, const int* __restrict__ dst,
                                 const int* __restrict__ off, int* __restrict__ fill, int* __restrict__ csr) {
    int e = blockIdx.x * 256 + threadIdx.x;
    if (e < E_EDGES) {
        int d = dst[e];
        int pos = atomicAdd(&fill[d], 1);
        csr[off[d] + pos] = src[e];
    }
}

// ---------------- fused GATv2 aggregation: 1 wave/node, 4 ch/thread, 4-edge pipeline ----------------
__global__ __launch_bounds__(256)
void gat_agg_kernel(const f16* __restrict__ xl, const f16* __restrict__ xr,
                    float* __restrict__ g, f16* __restrict__ g16,
                    const int* __restrict__ off, const int* __restrict__ csr,
                    const float* __restrict__ att,
                    const float* __restrict__ bias,
                    const float* __restrict__ lng,
                    const float* __restrict__ lnb)
{
    const int wv = threadIdx.x >> 6;
    const int ln = threadIdx.x & 63;           // channels 4ln..4ln+3; head = ln>>3
    const int n  = blockIdx.x * 4 + wv;
    if (n >= N_NODES) return;

    const f16x4* xl4 = (const f16x4*)xl;
    f16x4 xrv = ((const f16x4*)xr)[(size_t)n * 64 + ln];
    float xr0 = (float)xrv[0], xr1 = (float)xrv[1], xr2 = (float)xrv[2], xr3 = (float)xrv[3];
    float4 av = ((const float4*)att)[ln];

    float s = 0.f, o0 = 0.f, o1 = 0.f, o2 = 0.f, o3 = 0.f;

    auto proc = [&](f16x4 xv) {
        float x0 = (float)xv[0], x1 = (float)xv[1], x2 = (float)xv[2], x3 = (float)xv[3];
        float v0 = x0 + xr0; v0 = v0 > 0.f ? v0 : 0.2f * v0;
        float v1 = x1 + xr1; v1 = v1 > 0.f ? v1 : 0.2f * v1;
        float v2 = x2 + xr2; v2 = v2 > 0.f ? v2 : 0.2f * v2;
        float v3 = x3 + xr3; v3 = v3 > 0.f ? v3 : 0.2f * v3;
        float pr = av.x * v0 + av.y * v1 + av.z * v2 + av.w * v3;
        pr += __shfl_xor(pr, 4, 8);
        pr += __shfl_xor(pr, 2, 8);
        pr += __shfl_xor(pr, 1, 8);            // per-head logit (8 lanes = 32 ch)
        float e = __expf(pr);                   // logits bounded: no running max needed
        s += e;
        o0 += e * x0; o1 += e * x1; o2 += e * x2; o3 += e * x3;
    };

    int p = off[n], end = off[n + 1];
    for (; p + 4 <= end; p += 4) {
        int s0 = csr[p], s1 = csr[p + 1], s2 = csr[p + 2], s3 = csr[p + 3];
        f16x4 r0 = xl4[(size_t)s0 * 64 + ln];
        f16x4 r1 = xl4[(size_t)s1 * 64 + ln];
        f16x4 r2 = xl4[(size_t)s2 * 64 + ln];
        f16x4 r3 = xl4[(size_t)s3 * 64 + ln];
        proc(r0); proc(r1); proc(r2); proc(r3);
    }
    for (; p < end; ++p) {
        f16x4 r0 = xl4[(size_t)csr[p] * 64 + ln];
        proc(r0);
    }

    float inv = 1.f / (s + 1e-16f);
    float4 bi = ((const float4*)bias)[ln];
    float y0 = o0 * inv + bi.x;
    float y1 = o1 * inv + bi.y;
    float y2 = o2 * inv + bi.z;
    float y3 = o3 * inv + bi.w;

    // LayerNorm over 256 channels, pure wave-shuffle
    float s1 = y0 + y1 + y2 + y3;
    float s2 = y0 * y0 + y1 * y1 + y2 * y2 + y3 * y3;
#pragma unroll
    for (int d = 32; d; d >>= 1) { s1 += __shfl_xor(s1, d, 64); s2 += __shfl_xor(s2, d, 64); }
    float mu  = s1 * (1.f / HID);
    float ex2 = s2 * (1.f / HID);
    float rstd = rsqrtf(ex2 - mu * mu + 1e-5f);
    float4 lg = ((const float4*)lng)[ln];
    float4 lb = ((const float4*)lnb)[ln];
    float nv0 = (y0 - mu) * rstd * lg.x + lb.x; nv0 = nv0 > 0.f ? nv0 : 0.1f * nv0;
    float nv1 = (y1 - mu) * rstd * lg.y + lb.y; nv1 = nv1 > 0.f ? nv1 : 0.1f * nv1;
    float nv2 = (y2 - mu) * rstd * lg.z + lb.z; nv2 = nv2 > 0.f ? nv2 : 0.1f * nv2;
    float nv3 = (y3 - mu) * rstd * lg.w + lb.w; nv3 = nv3 > 0.f ? nv3 : 0.1f * nv3;

    float4 gv = ((const float4*)g)[(size_t)n * 64 + ln];
    float g0 = nv0 + gv.x, g1 = nv1 + gv.y, g2 = nv2 + gv.z, g3 = nv3 + gv.w;
    ((float4*)g)[(size_t)n * 64 + ln] = make_float4(g0, g1, g2, g3);
    f16x4 gh; gh[0] = (f16)g0; gh[1] = (f16)g1; gh[2] = (f16)g2; gh[3] = (f16)g3;
    ((f16x4*)g16)[(size_t)n * 64 + ln] = gh;
}

// ---------------- final head dot: [N,64] f16 @ [64,1] + b ----------------
__global__ __launch_bounds__(256)
void head_final_kernel(const f16* __restrict__ t3, const float* __restrict__ w4,
                       const float* __restrict__ b4, float* __restrict__ out)
{
    int row = blockIdx.x * 4 + (threadIdx.x >> 6);
    int lane = threadIdx.x & 63;
    float v = 0.f;
    if (row < N_NODES) v = (float)t3[(size_t)row * 64 + lane] * w4[lane];
#pragma unroll
    for (int d = 32; d; d >>= 1) v += __shfl_xor(v, d, 64);
    if (row < N_NODES && lane == 0) out[row] = v + b4[0];
}

static inline size_t align_up(size_t v, size_t a) { return (v + a - 1) & ~(a - 1); }

extern "C" void kernel_launch(void* const* d_in, const int* in_sizes, int n_in,
                              void* d_out, int out_size, void* d_ws, size_t ws_size,
                              hipStream_t stream)
{
    const float* x      = (const float*)d_in[0];
    const int*   ei     = (const int*)d_in[1];
    const float* mlp_w1 = (const float*)d_in[2];
    const float* mlp_b1 = (const float*)d_in[3];
    const float* bn1_g  = (const float*)d_in[4];
    const float* bn1_b  = (const float*)d_in[5];
    const float* mlp_w2 = (const float*)d_in[6];
    const float* mlp_b2 = (const float*)d_in[7];
    const float* bn2_g  = (const float*)d_in[8];
    const float* bn2_b  = (const float*)d_in[9];
    const float* mlp_w3 = (const float*)d_in[10];
    const float* mlp_b3 = (const float*)d_in[11];
    const float* gat_wl = (const float*)d_in[12];
    const float* gat_bl = (const float*)d_in[13];
    const float* gat_wr = (const float*)d_in[14];
    const float* gat_br = (const float*)d_in[15];
    const float* gat_att  = (const float*)d_in[16];
    const float* gat_bias = (const float*)d_in[17];
    const float* ln_g   = (const float*)d_in[18];
    const float* ln_b   = (const float*)d_in[19];
    const float* head_w1 = (const float*)d_in[20];
    const float* head_b1 = (const float*)d_in[21];
    const float* hbn1_g  = (const float*)d_in[22];
    const float* hbn1_b  = (const float*)d_in[23];
    const float* head_w2 = (const float*)d_in[24];
    const float* head_b2 = (const float*)d_in[25];
    const float* hbn2_g  = (const float*)d_in[26];
    const float* hbn2_b  = (const float*)d_in[27];
    const float* head_w3 = (const float*)d_in[28];
    const float* head_b3 = (const float*)d_in[29];
    const float* head_w4 = (const float*)d_in[30];
    const float* head_b4 = (const float*)d_in[31];
    float* out = (float*)d_out;

    // ---- workspace layout ----
    char* w = (char*)d_ws;
    size_t p = 0;
    int* off  = (int*)(w + p); p = align_up(p + (N_NODES + 1) * sizeof(int), 64);
    int* fill = (int*)(w + p); p = align_up(p + N_NODES * sizeof(int), 64);
    int* csr  = (int*)(w + p); p = align_up(p + E_TOT * sizeof(int), 64);
    float* g32 = (float*)(w + p); p = align_up(p + (size_t)N_NODES * HID * 4, 64);
    auto halloc = [&](size_t elems) {
        f16* q = (f16*)(w + p);
        p = align_up(p + elems * 2, 1024);
        return q;
    };
    f16* x16     = halloc((size_t)N_NODES * IN_CH);
    f16* h1      = halloc((size_t)N_NODES * HID);   // MLP1 out / head1 out
    f16* h2      = halloc((size_t)N_NODES * HID);   // MLP2 out / head2 out
    f16* x_mlp16 = halloc((size_t)N_NODES * HID);
    f16* g16     = halloc((size_t)N_NODES * HID);
    f16* xl16    = halloc((size_t)N_NODES * HID);
    f16* xr16    = halloc((size_t)N_NODES * HID);
    f16* t3      = halloc((size_t)N_NODES * 64);    // head3 out
    f16* wt_mlp1 = halloc((size_t)IN_CH * HID);
    f16* wt_mlp2 = halloc((size_t)HID * HID);
    f16* wt_mlp3 = halloc((size_t)HID * HID);
    f16* wt_g[4];
    for (int i = 0; i < 4; ++i) wt_g[i] = halloc((size_t)HID * 2 * HID);
    f16* wt_h1 = halloc((size_t)2 * HID * HID);
    f16* wt_h2 = halloc((size_t)HID * (HID / 2));
    f16* wt_h3 = halloc((size_t)(HID / 2) * (HID / 4));
    (void)ws_size; (void)in_sizes; (void)n_in; (void)out_size;

    const int* e_src = ei;
    const int* e_dst = ei + E_EDGES;

    dim3 blk(256);
    dim3 gM((N_NODES + 15) / 16);      // 1250

    // ---- weight prep (fp32 -> fp16 fragment-major; wl+wr fused per layer) ----
    WDescs ds;
    ds.d[0]  = { mlp_w1, wt_mlp1, IN_CH, HID, 16, 0 };
    ds.d[1]  = { mlp_w2, wt_mlp2, HID, HID, 16, 0 };
    ds.d[2]  = { mlp_w3, wt_mlp3, HID, HID, 16, 0 };
    for (int i = 0; i < 4; ++i) {
        ds.d[3 + 2 * i] = { gat_wl + (size_t)i * HID * HID, wt_g[i], HID, HID, 32, 0 };
        ds.d[4 + 2 * i] = { gat_wr + (size_t)i * HID * HID, wt_g[i], HID, HID, 32, 16 };
    }
    ds.d[11] = { head_w1, wt_h1, 2 * HID, HID, 16, 0 };
    ds.d[12] = { head_w2, wt_h2, HID, HID / 2, 8, 0 };
    ds.d[13] = { head_w3, wt_h3, HID / 2, HID / 4, 4, 0 };
    {
        dim3 gp((2 * HID * HID + 255) / 256, 14);
        wprep_kernel<<<gp, blk, 0, stream>>>(ds);
    }
    cvt32to16_kernel<<<(N_NODES * IN_CH + 255) / 256, blk, 0, stream>>>(x, x16, N_NODES * IN_CH);

    // ---- CSR by destination ----
    deg_init_kernel<<<(N_NODES + 255) / 256, blk, 0, stream>>>(fill);
    deg_count_kernel<<<(E_EDGES + 255) / 256, blk, 0, stream>>>(e_dst, fill);
    scan_kernel<<<1, 1024, 0, stream>>>(fill, off);
    self_fill_kernel<<<(N_NODES + 255) / 256, blk, 0, stream>>>(off, fill, csr);
    edge_fill_kernel<<<(E_EDGES + 255) / 256, blk, 0, stream>>>(e_src, e_dst, off, fill, csr);

    // ---- MLP stem (all f16 I/O) ----
    gemm_kernel<2, 16, 8><<<gM, 512, 0, stream>>>(x16, IN_CH, nullptr, 0, wt_mlp1, mlp_b1, mlp_b1,
                                                  bn1_g, bn1_b, h1, nullptr, HID, N_NODES, EP_BN_LRELU);
    gemm_kernel<2, 16, 8><<<gM, 512, 0, stream>>>(h1, HID, nullptr, 0, wt_mlp2, mlp_b2, mlp_b2,
                                                  bn2_g, bn2_b, h2, nullptr, HID, N_NODES, EP_BN_LRELU);
    gemm_kernel<2, 16, 8><<<gM, 512, 0, stream>>>(h2, HID, nullptr, 0, wt_mlp3, mlp_b3, mlp_b3,
                                                  nullptr, nullptr, x_mlp16, nullptr, HID, N_NODES, EP_BIAS);
    cvt16to32_kernel<<<(N_NODES * HID + 255) / 256, blk, 0, stream>>>(x_mlp16, g32, N_NODES * HID);
    hipMemcpyAsync(g16, x_mlp16, (size_t)N_NODES * HID * 2, hipMemcpyDeviceToDevice, stream);

    // ---- GAT layers (fused wl|wr dual-output GEMM + fused aggregation) ----
    for (int i = 0; i < 4; ++i) {
        gemm_kernel<4, 32, 8><<<gM, 512, 0, stream>>>(g16, HID, nullptr, 0, wt_g[i],
                                                      gat_bl + i * HID, gat_br + i * HID,
                                                      nullptr, nullptr, xl16, xr16, HID, N_NODES, EP_BIAS);
        gat_agg_kernel<<<(N_NODES + 3) / 4, blk, 0, stream>>>(xl16, xr16, g32, g16, off, csr,
                                                              gat_att + i * HID, gat_bias + i * HID,
                                                              ln_g + i * HID, ln_b + i * HID);
    }

    // ---- regression head ----
    gemm_kernel<2, 16, 8><<<gM, 512, 0, stream>>>(x_mlp16, HID, g16, HID, wt_h1, head_b1, head_b1,
                                                  hbn1_g, hbn1_b, h1, nullptr, HID, N_NODES, EP_BN_LRELU);
    gemm_kernel<1, 8, 8><<<gM, 512, 0, stream>>>(h1, HID, nullptr, 0, wt_h2, head_b2, head_b2,
                                                 hbn2_g, hbn2_b, h2, nullptr, HID / 2, N_NODES, EP_BN_LRELU);
    gemm_kernel<1, 4, 4><<<gM, 256, 0, stream>>>(h2, HID / 2, nullptr, 0, wt_h3, head_b3, head_b3,
                                                 nullptr, nullptr, t3, nullptr, HID / 4, N_NODES, EP_LRELU);
    head_final_kernel<<<(N_NODES + 3) / 4, blk, 0, stream>>>(t3, head_w4, head_b4, out);
}

// Round 9
// 529.015 us; speedup vs baseline: 3.2527x; 1.1071x over previous
//
#include <hip/hip_runtime.h>
#include <hip/hip_bf16.h>

#define N_NODES 20000
#define E_EDGES 320000
#define E_TOT   (E_EDGES + N_NODES)
#define IN_CH   128
#define HID     256
#define HEADS   8
#define CPH     32

enum { EP_BIAS = 0, EP_BN_LRELU = 1, EP_LRELU = 2 };

typedef _Float16 f16;
typedef f16  f16x2 __attribute__((ext_vector_type(2)));
typedef f16  f16x4 __attribute__((ext_vector_type(4)));
typedef f16  f16x8 __attribute__((ext_vector_type(8)));
typedef float f32x4 __attribute__((ext_vector_type(4)));

__device__ __forceinline__ f16x2 h2max(f16x2 a, f16x2 b) {
#if __has_builtin(__builtin_elementwise_max)
    return __builtin_elementwise_max(a, b);
#else
    f16x2 r; r[0] = a[0] > b[0] ? a[0] : b[0]; r[1] = a[1] > b[1] ? a[1] : b[1]; return r;
#endif
}
__device__ __forceinline__ float hdot2(f16x2 a, f16x2 b, float c) {
#if __has_builtin(__builtin_amdgcn_fdot2)
    return __builtin_amdgcn_fdot2(a, b, c, false);
#else
    return c + (float)a[0] * (float)b[0] + (float)a[1] * (float)b[1];
#endif
}

// ---------------- weight prep: fp32 [K,Nc] -> fp16 fragment-major ----------------
// Fragment stream: [kb][ks][ct_global][lane][8 f16], ct_global = ct0 + ct_local.
struct WDesc { const float* src; f16* dst; int K; int Nc; int NTOT; int ct0; };
struct WDescs { WDesc d[14]; };

__global__ __launch_bounds__(256)
void wprep_kernel(WDescs ds) {
    WDesc w = ds.d[blockIdx.y];
    int total = w.K * w.Nc;
    int i = blockIdx.x * 256 + threadIdx.x;
    if (i < total) {
        int NT_local = w.Nc >> 4;
        int e  = i & 7;
        int l  = (i >> 3) & 63;
        int r  = i >> 9;
        int ct = r % NT_local;
        int q  = r / NT_local;
        int ks = q & 1;
        int kb = q >> 1;
        int n  = ct * 16 + (l & 15);
        int k  = kb * 64 + ks * 32 + ((l >> 4) << 3) + e;
        size_t di = (((size_t)(kb * 2 + ks) * w.NTOT + w.ct0 + ct) << 9) + (l << 3) + e;
        w.dst[di] = (f16)w.src[(size_t)k * w.Nc + n];
    }
}

__global__ void cvt32to16_kernel(const float* __restrict__ in, f16* __restrict__ out, int n) {
    int i = blockIdx.x * 256 + threadIdx.x;
    if (i < n) out[i] = (f16)in[i];
}

// ---------------- barrier-free fp16 MFMA GEMM ----------------
// Block = RT*16 rows; WAVES waves split NTOT col-tiles (NT each), each wave does RT row-frags.
// Dual out (cols>=NcA -> out16B); optional dup16/out32 mirrors; optional fused dot epilogue
// (outdot != null, requires RT==1): out[row] = sum_col(v*dotw[col]) + dotb[0].
template<int NT, int NTOT, int WAVES, int RT>
__global__ __launch_bounds__(WAVES * 64)
void gemm_kernel(const f16* __restrict__ A1, int K1,
                 const f16* __restrict__ A2, int K2,
                 const f16* __restrict__ Wf,
                 const float* __restrict__ biasA,
                 const float* __restrict__ biasB,
                 const float* __restrict__ bng,
                 const float* __restrict__ bnb,
                 f16* __restrict__ out16A,
                 f16* __restrict__ out16B,
                 f16* __restrict__ dup16,
                 float* __restrict__ out32,
                 const float* __restrict__ dotw,
                 const float* __restrict__ dotb,
                 float* __restrict__ outdot,
                 int NcA, int M, int mode)
{
    __shared__ float red[16][65];
    const int K = K1 + K2;
    const int tid  = threadIdx.x;
    const int wave = tid >> 6;
    const int lane = tid & 63;
    const int quad = lane >> 4;
    const int bm = blockIdx.x * (RT * 16);

    int rowA[RT];
#pragma unroll
    for (int t = 0; t < RT; ++t) {
        int r = bm + t * 16 + (lane & 15);
        rowA[t] = r < M ? r : M - 1;
    }

    f32x4 acc[RT][NT];
#pragma unroll
    for (int t = 0; t < RT; ++t)
#pragma unroll
        for (int j = 0; j < NT; ++j) acc[t][j] = (f32x4){0.f, 0.f, 0.f, 0.f};

    const int KB = K >> 6;
#pragma unroll 2
    for (int kb = 0; kb < KB; ++kb) {
#pragma unroll
        for (int ks = 0; ks < 2; ++ks) {
            int k = kb * 64 + ks * 32 + quad * 8;
            f16x8 a[RT];
#pragma unroll
            for (int t = 0; t < RT; ++t) {
                const f16* ap = (k < K1) ? &A1[(size_t)rowA[t] * K1 + k]
                                         : &A2[(size_t)rowA[t] * K2 + (k - K1)];
                a[t] = *(const f16x8*)ap;
            }
            const f16* bp = Wf + (((size_t)(kb * 2 + ks) * NTOT + wave * NT) << 9) + lane * 8;
#pragma unroll
            for (int ct = 0; ct < NT; ++ct) {
                f16x8 b = *(const f16x8*)(bp + ((size_t)ct << 9));
#pragma unroll
                for (int t = 0; t < RT; ++t)
                    acc[t][ct] = __builtin_amdgcn_mfma_f32_16x16x32_f16(a[t], b, acc[t][ct], 0, 0, 0);
            }
        }
    }

    // epilogue: C/D layout col=lane&15, row=quad*4+reg
    const int c0 = lane & 15;
    const int NcB = NTOT * 16 - NcA;
#pragma unroll
    for (int t = 0; t < RT; ++t) {
        const int r0 = bm + t * 16 + (quad << 2);
#pragma unroll
        for (int ct = 0; ct < NT; ++ct) {
            int col = (wave * NT + ct) * 16 + c0;
            bool isB = col >= NcA;
            int colL = isB ? col - NcA : col;
            float bv = isB ? biasB[colL] : biasA[colL];
            float sc = 1.f, sh = 0.f;
            if (mode == EP_BN_LRELU) {
                sc = bng[col] * rsqrtf(1.f + 1e-5f);
                sh = bnb[col];
            }
            f16* Cout = isB ? out16B : out16A;
            int stride = isB ? NcB : NcA;
#pragma unroll
            for (int reg = 0; reg < 4; ++reg) {
                int row = r0 + reg;
                if (row < M) {
                    float v = acc[t][ct][reg] + bv;
                    if (mode == EP_BN_LRELU) { v = v * sc + sh; v = v > 0.f ? v : 0.1f * v; }
                    else if (mode == EP_LRELU) { v = v > 0.f ? v : 0.1f * v; }
                    if (outdot) {
                        red[(quad << 2) + reg][col] = v * dotw[col];
                    } else {
                        Cout[(size_t)row * stride + colL] = (f16)v;
                        if (dup16) dup16[(size_t)row * stride + colL] = (f16)v;
                        if (out32) out32[(size_t)row * stride + colL] = v;
                    }
                }
            }
        }
    }

    if (outdot) {   // RT==1, NTOT*16 == 64
        __syncthreads();
        if (wave == 0) {
            int r = lane & 15, q = lane >> 4;
            float psum = 0.f;
#pragma unroll
            for (int j = 0; j < 16; ++j) psum += red[r][q * 16 + j];
            psum += __shfl_xor(psum, 16, 64);
            psum += __shfl_xor(psum, 32, 64);
            if (lane < 16) {
                int row = bm + r;
                if (row < M) outdot[row] = psum + dotb[0];
            }
        }
    }
}

// ---------------- CSR build ----------------
__global__ void deg_init_kernel(int* __restrict__ cnt) {
    int i = blockIdx.x * 256 + threadIdx.x;
    if (i < N_NODES) cnt[i] = 1;   // self loop
}
__global__ void deg_count_kernel(const int* __restrict__ dst, int* __restrict__ cnt) {
    int e = blockIdx.x * 256 + threadIdx.x;
    if (e < E_EDGES) atomicAdd(&cnt[dst[e]], 1);
}
// wave-shuffle hierarchical scan (exclusive) over N_NODES, single block of 1024
__global__ __launch_bounds__(1024)
void scan_kernel(const int* __restrict__ cnt, int* __restrict__ off) {
    __shared__ int wsum[16];
    __shared__ int wpre[16];
    __shared__ int tot_s;
    __shared__ int carry_s;
    const int tid = threadIdx.x, wv = tid >> 6, ln = tid & 63;
    if (tid == 0) carry_s = 0;
    __syncthreads();
    for (int base = 0; base < N_NODES; base += 1024) {
        int i = base + tid;
        int v = (i < N_NODES) ? cnt[i] : 0;
        int s = v;
#pragma unroll
        for (int d = 1; d < 64; d <<= 1) { int t = __shfl_up(s, d, 64); if (ln >= d) s += t; }
        if (ln == 63) wsum[wv] = s;
        __syncthreads();
        if (tid < 16) {
            int t = wsum[tid];
            int sc = t;
#pragma unroll
            for (int d = 1; d < 16; d <<= 1) { int u = __shfl_up(sc, d, 16); if (tid >= d) sc += u; }
            wpre[tid] = sc - t;
            if (tid == 15) tot_s = sc;
        }
        __syncthreads();
        if (i < N_NODES) off[i] = carry_s + wpre[wv] + s - v;
        __syncthreads();
        if (tid == 0) carry_s += tot_s;
        __syncthreads();
    }
    if (threadIdx.x == 0) off[N_NODES] = carry_s;
}
__global__ void self_fill_kernel(const int* __restrict__ off, int* __restrict__ fill, int* __restrict__ csr) {
    int i = blockIdx.x * 256 + threadIdx.x;
    if (i < N_NODES) { csr[off[i]] = i; fill[i] = 1; }
}
__global__ void edge_fill_kernel(const int* __restrict__ src, const int* __restrict__ dst,
                                 const int* __restrict__ off, int* __restrict__ fill, int* __restrict__ csr) {
    int e = blockIdx.x * 256 + threadIdx.x;
    if (e < E_EDGES) {
        int d = dst[e];
        int pos = atomicAdd(&fill[d], 1);
        csr[off[d] + pos] = src[e];
    }
}

// ---------------- fused GATv2 aggregation: 1 wave/node, 4 ch/thread, packed-f16 math ----------------
__global__ __launch_bounds__(256)
void gat_agg_kernel(const f16* __restrict__ xl, const f16* __restrict__ xr,
                    float* __restrict__ g, f16* __restrict__ g16,
                    const int* __restrict__ off, const int* __restrict__ csr,
                    const float* __restrict__ att,
                    const float* __restrict__ bias,
                    const float* __restrict__ lng,
                    const float* __restrict__ lnb)
{
    const int wv = threadIdx.x >> 6;
    const int ln = threadIdx.x & 63;           // channels 4ln..4ln+3; head = ln>>3
    const int n  = blockIdx.x * 4 + wv;
    if (n >= N_NODES) return;

    const f16x4* xl4 = (const f16x4*)xl;
    f16x4 xrv = ((const f16x4*)xr)[(size_t)n * 64 + ln];
    f16x2 xr01; xr01[0] = xrv[0]; xr01[1] = xrv[1];
    f16x2 xr23; xr23[0] = xrv[2]; xr23[1] = xrv[3];
    float4 avf = ((const float4*)att)[ln];
    f16x2 av01; av01[0] = (f16)avf.x; av01[1] = (f16)avf.y;
    f16x2 av23; av23[0] = (f16)avf.z; av23[1] = (f16)avf.w;
    const f16x2 k02 = { (f16)0.2f, (f16)0.2f };

    float s = 0.f, o0 = 0.f, o1 = 0.f, o2 = 0.f, o3 = 0.f;

    auto proc = [&](f16x4 xv) {
        f16x2 x01; x01[0] = xv[0]; x01[1] = xv[1];
        f16x2 x23; x23[0] = xv[2]; x23[1] = xv[3];
        f16x2 v01 = x01 + xr01;
        f16x2 v23 = x23 + xr23;
        f16x2 l01 = h2max(v01, v01 * k02);     // leaky 0.2 (packed)
        f16x2 l23 = h2max(v23, v23 * k02);
        float pr = hdot2(l01, av01, hdot2(l23, av23, 0.f));
        pr += __shfl_xor(pr, 4, 8);
        pr += __shfl_xor(pr, 2, 8);
        pr += __shfl_xor(pr, 1, 8);            // per-head logit (8 lanes = 32 ch)
        float e = __expf(pr);                   // logits bounded: no running max needed
        s += e;
        o0 += e * (float)xv[0]; o1 += e * (float)xv[1];
        o2 += e * (float)xv[2]; o3 += e * (float)xv[3];
    };

    int p = off[n], end = off[n + 1];
    for (; p + 4 <= end; p += 4) {
        int s0 = csr[p], s1 = csr[p + 1], s2 = csr[p + 2], s3 = csr[p + 3];
        f16x4 r0 = xl4[(size_t)s0 * 64 + ln];
        f16x4 r1 = xl4[(size_t)s1 * 64 + ln];
        f16x4 r2 = xl4[(size_t)s2 * 64 + ln];
        f16x4 r3 = xl4[(size_t)s3 * 64 + ln];
        proc(r0); proc(r1); proc(r2); proc(r3);
    }
    for (; p < end; ++p) {
        f16x4 r0 = xl4[(size_t)csr[p] * 64 + ln];
        proc(r0);
    }

    float inv = 1.f / (s + 1e-16f);
    float4 bi = ((const float4*)bias)[ln];
    float y0 = o0 * inv + bi.x;
    float y1 = o1 * inv + bi.y;
    float y2 = o2 * inv + bi.z;
    float y3 = o3 * inv + bi.w;

    // LayerNorm over 256 channels, pure wave-shuffle
    float s1 = y0 + y1 + y2 + y3;
    float s2 = y0 * y0 + y1 * y1 + y2 * y2 + y3 * y3;
#pragma unroll
    for (int d = 32; d; d >>= 1) { s1 += __shfl_xor(s1, d, 64); s2 += __shfl_xor(s2, d, 64); }
    float mu  = s1 * (1.f / HID);
    float ex2 = s2 * (1.f / HID);
    float rstd = rsqrtf(ex2 - mu * mu + 1e-5f);
    float4 lg = ((const float4*)lng)[ln];
    float4 lb = ((const float4*)lnb)[ln];
    float nv0 = (y0 - mu) * rstd * lg.x + lb.x; nv0 = nv0 > 0.f ? nv0 : 0.1f * nv0;
    float nv1 = (y1 - mu) * rstd * lg.y + lb.y; nv1 = nv1 > 0.f ? nv1 : 0.1f * nv1;
    float nv2 = (y2 - mu) * rstd * lg.z + lb.z; nv2 = nv2 > 0.f ? nv2 : 0.1f * nv2;
    float nv3 = (y3 - mu) * rstd * lg.w + lb.w; nv3 = nv3 > 0.f ? nv3 : 0.1f * nv3;

    float4 gv = ((const float4*)g)[(size_t)n * 64 + ln];
    float g0 = nv0 + gv.x, g1 = nv1 + gv.y, g2 = nv2 + gv.z, g3 = nv3 + gv.w;
    ((float4*)g)[(size_t)n * 64 + ln] = make_float4(g0, g1, g2, g3);
    f16x4 gh; gh[0] = (f16)g0; gh[1] = (f16)g1; gh[2] = (f16)g2; gh[3] = (f16)g3;
    ((f16x4*)g16)[(size_t)n * 64 + ln] = gh;
}

static inline size_t align_up(size_t v, size_t a) { return (v + a - 1) & ~(a - 1); }

extern "C" void kernel_launch(void* const* d_in, const int* in_sizes, int n_in,
                              void* d_out, int out_size, void* d_ws, size_t ws_size,
                              hipStream_t stream)
{
    const float* x      = (const float*)d_in[0];
    const int*   ei     = (const int*)d_in[1];
    const float* mlp_w1 = (const float*)d_in[2];
    const float* mlp_b1 = (const float*)d_in[3];
    const float* bn1_g  = (const float*)d_in[4];
    const float* bn1_b  = (const float*)d_in[5];
    const float* mlp_w2 = (const float*)d_in[6];
    const float* mlp_b2 = (const float*)d_in[7];
    const float* bn2_g  = (const float*)d_in[8];
    const float* bn2_b  = (const float*)d_in[9];
    const float* mlp_w3 = (const float*)d_in[10];
    const float* mlp_b3 = (const float*)d_in[11];
    const float* gat_wl = (const float*)d_in[12];
    const float* gat_bl = (const float*)d_in[13];
    const float* gat_wr = (const float*)d_in[14];
    const float* gat_br = (const float*)d_in[15];
    const float* gat_att  = (const float*)d_in[16];
    const float* gat_bias = (const float*)d_in[17];
    const float* ln_g   = (const float*)d_in[18];
    const float* ln_b   = (const float*)d_in[19];
    const float* head_w1 = (const float*)d_in[20];
    const float* head_b1 = (const float*)d_in[21];
    const float* hbn1_g  = (const float*)d_in[22];
    const float* hbn1_b  = (const float*)d_in[23];
    const float* head_w2 = (const float*)d_in[24];
    const float* head_b2 = (const float*)d_in[25];
    const float* hbn2_g  = (const float*)d_in[26];
    const float* hbn2_b  = (const float*)d_in[27];
    const float* head_w3 = (const float*)d_in[28];
    const float* head_b3 = (const float*)d_in[29];
    const float* head_w4 = (const float*)d_in[30];
    const float* head_b4 = (const float*)d_in[31];
    float* out = (float*)d_out;

    // ---- workspace layout ----
    char* w = (char*)d_ws;
    size_t p = 0;
    int* off  = (int*)(w + p); p = align_up(p + (N_NODES + 1) * sizeof(int), 64);
    int* fill = (int*)(w + p); p = align_up(p + N_NODES * sizeof(int), 64);
    int* csr  = (int*)(w + p); p = align_up(p + E_TOT * sizeof(int), 64);
    float* g32 = (float*)(w + p); p = align_up(p + (size_t)N_NODES * HID * 4, 64);
    auto halloc = [&](size_t elems) {
        f16* q = (f16*)(w + p);
        p = align_up(p + elems * 2, 1024);
        return q;
    };
    f16* x16     = halloc((size_t)N_NODES * IN_CH);
    f16* h1      = halloc((size_t)N_NODES * HID);   // MLP1 out / head1 out
    f16* h2      = halloc((size_t)N_NODES * HID);   // MLP2 out / head2 out
    f16* x_mlp16 = halloc((size_t)N_NODES * HID);
    f16* g16     = halloc((size_t)N_NODES * HID);
    f16* xl16    = halloc((size_t)N_NODES * HID);
    f16* xr16    = halloc((size_t)N_NODES * HID);
    f16* wt_mlp1 = halloc((size_t)IN_CH * HID);
    f16* wt_mlp2 = halloc((size_t)HID * HID);
    f16* wt_mlp3 = halloc((size_t)HID * HID);
    f16* wt_g[4];
    for (int i = 0; i < 4; ++i) wt_g[i] = halloc((size_t)HID * 2 * HID);
    f16* wt_h1 = halloc((size_t)2 * HID * HID);
    f16* wt_h2 = halloc((size_t)HID * (HID / 2));
    f16* wt_h3 = halloc((size_t)(HID / 2) * (HID / 4));
    (void)ws_size; (void)in_sizes; (void)n_in; (void)out_size;

    const int* e_src = ei;
    const int* e_dst = ei + E_EDGES;

    dim3 blk(256);
    dim3 gM32((N_NODES + 31) / 32);    // 625
    dim3 gM16((N_NODES + 15) / 16);    // 1250

    // ---- weight prep (fp32 -> fp16 fragment-major; wl+wr fused per layer) ----
    WDescs ds;
    ds.d[0]  = { mlp_w1, wt_mlp1, IN_CH, HID, 16, 0 };
    ds.d[1]  = { mlp_w2, wt_mlp2, HID, HID, 16, 0 };
    ds.d[2]  = { mlp_w3, wt_mlp3, HID, HID, 16, 0 };
    for (int i = 0; i < 4; ++i) {
        ds.d[3 + 2 * i] = { gat_wl + (size_t)i * HID * HID, wt_g[i], HID, HID, 32, 0 };
        ds.d[4 + 2 * i] = { gat_wr + (size_t)i * HID * HID, wt_g[i], HID, HID, 32, 16 };
    }
    ds.d[11] = { head_w1, wt_h1, 2 * HID, HID, 16, 0 };
    ds.d[12] = { head_w2, wt_h2, HID, HID / 2, 8, 0 };
    ds.d[13] = { head_w3, wt_h3, HID / 2, HID / 4, 4, 0 };
    {
        dim3 gp((2 * HID * HID + 255) / 256, 14);
        wprep_kernel<<<gp, blk, 0, stream>>>(ds);
    }
    cvt32to16_kernel<<<(N_NODES * IN_CH + 255) / 256, blk, 0, stream>>>(x, x16, N_NODES * IN_CH);

    // ---- CSR by destination ----
    deg_init_kernel<<<(N_NODES + 255) / 256, blk, 0, stream>>>(fill);
    deg_count_kernel<<<(E_EDGES + 255) / 256, blk, 0, stream>>>(e_dst, fill);
    scan_kernel<<<1, 1024, 0, stream>>>(fill, off);
    self_fill_kernel<<<(N_NODES + 255) / 256, blk, 0, stream>>>(off, fill, csr);
    edge_fill_kernel<<<(E_EDGES + 255) / 256, blk, 0, stream>>>(e_src, e_dst, off, fill, csr);

    // ---- MLP stem (f16 I/O; MLP3 writes x_mlp16 + g16 + g32 in one epilogue) ----
    gemm_kernel<2, 16, 8, 2><<<gM32, 512, 0, stream>>>(x16, IN_CH, nullptr, 0, wt_mlp1, mlp_b1, mlp_b1,
        bn1_g, bn1_b, h1, nullptr, nullptr, nullptr, nullptr, nullptr, nullptr, HID, N_NODES, EP_BN_LRELU);
    gemm_kernel<2, 16, 8, 2><<<gM32, 512, 0, stream>>>(h1, HID, nullptr, 0, wt_mlp2, mlp_b2, mlp_b2,
        bn2_g, bn2_b, h2, nullptr, nullptr, nullptr, nullptr, nullptr, nullptr, HID, N_NODES, EP_BN_LRELU);
    gemm_kernel<2, 16, 8, 2><<<gM32, 512, 0, stream>>>(h2, HID, nullptr, 0, wt_mlp3, mlp_b3, mlp_b3,
        nullptr, nullptr, x_mlp16, nullptr, g16, g32, nullptr, nullptr, nullptr, HID, N_NODES, EP_BIAS);

    // ---- GAT layers (fused wl|wr dual-output GEMM + fused aggregation) ----
    for (int i = 0; i < 4; ++i) {
        gemm_kernel<4, 32, 8, 2><<<gM32, 512, 0, stream>>>(g16, HID, nullptr, 0, wt_g[i],
            gat_bl + i * HID, gat_br + i * HID, nullptr, nullptr,
            xl16, xr16, nullptr, nullptr, nullptr, nullptr, nullptr, HID, N_NODES, EP_BIAS);
        gat_agg_kernel<<<(N_NODES + 3) / 4, blk, 0, stream>>>(xl16, xr16, g32, g16, off, csr,
                                                              gat_att + i * HID, gat_bias + i * HID,
                                                              ln_g + i * HID, ln_b + i * HID);
    }

    // ---- regression head (head3 GEMM fuses the final [64]x[64,1] dot) ----
    gemm_kernel<2, 16, 8, 2><<<gM32, 512, 0, stream>>>(x_mlp16, HID, g16, HID, wt_h1, head_b1, head_b1,
        hbn1_g, hbn1_b, h1, nullptr, nullptr, nullptr, nullptr, nullptr, nullptr, HID, N_NODES, EP_BN_LRELU);
    gemm_kernel<1, 8, 8, 2><<<gM32, 512, 0, stream>>>(h1, HID, nullptr, 0, wt_h2, head_b2, head_b2,
        hbn2_g, hbn2_b, h2, nullptr, nullptr, nullptr, nullptr, nullptr, nullptr, HID / 2, N_NODES, EP_BN_LRELU);
    gemm_kernel<1, 4, 4, 1><<<gM16, 256, 0, stream>>>(h2, HID / 2, nullptr, 0, wt_h3, head_b3, head_b3,
        nullptr, nullptr, nullptr, nullptr, nullptr, nullptr, head_w4, head_b4, out, HID / 4, N_NODES, EP_LRELU);
}